// Round 17
// baseline (134.120 us; speedup 1.0000x reference)
//
#include <hip/hip_runtime.h>
#include <math.h>

#define Bdim 8
#define Cdim 128
#define Ndim 16384
#define Kdim 8

typedef __attribute__((ext_vector_type(8))) short short8;
typedef __attribute__((ext_vector_type(4))) float f32x4;

__device__ __forceinline__ unsigned rne16(float x) {
  unsigned u = __float_as_uint(x);
  return (u + 0x7FFFu + ((u >> 16) & 1u)) >> 16;
}

// ---------------- kernel 0: merged prep (wsplit + wprep + zero cnt) ------------
__global__ void __launch_bounds__(256) k_prep(
    const float* __restrict__ W, unsigned short* __restrict__ Whs,
    unsigned short* __restrict__ Wls,
    const float* __restrict__ p0, const float* __restrict__ p1, const float* __restrict__ p2,
    const float* __restrict__ p3, const float* __restrict__ p4, const float* __restrict__ p5,
    const float* __restrict__ p6, const float* __restrict__ p7, const float* __restrict__ p8,
    unsigned short* __restrict__ Wbf, int* __restrict__ cnt) {
  int blk = blockIdx.x, t = threadIdx.x;
  if (blk < 64) {
    int idx = blk * 256 + t;  // 16384, [o][c] row-major
    int o = idx >> 7, c = idx & 127;
    float v = W[idx];
    unsigned u = __float_as_uint(v);
    unsigned rh = (u + 0x7FFFu + ((u >> 16) & 1u)) & 0xFFFF0000u;
    float vh = __uint_as_float(rh);
    float r = v - vh;  // exact
    unsigned u2 = __float_as_uint(r);
    unsigned rl = (u2 + 0x7FFFu + ((u2 >> 16) & 1u)) >> 16;
    int pos = o * 128 + (((c >> 3) ^ (o & 7)) << 3) + (c & 7);
    Whs[pos] = (unsigned short)(rh >> 16);
    Wls[pos] = (unsigned short)rl;
    if (blk == 0 && t < Bdim * Kdim) cnt[t] = 0;
  } else {
    int m = (blk - 64) >> 6;                 // 9 matrices x 64 blocks
    int i = ((blk - 64) & 63) * 256 + t;
    const float* mp = m == 0 ? p0 : m == 1 ? p1 : m == 2 ? p2 : m == 3 ? p3 : m == 4 ? p4
                    : m == 5 ? p5 : m == 6 ? p6 : m == 7 ? p7 : p8;
    Wbf[m * 16384 + i] = (unsigned short)rne16(mp[i]);
  }
}

// ---------------- kernel 1: bin assignment + counts ----------------
__global__ void __launch_bounds__(256) k_bin(const float* __restrict__ logits,
                                             signed char* __restrict__ kbin,
                                             int* __restrict__ cnt) {
  __shared__ int h[Kdim];
  int tid = threadIdx.x;
  if (tid < Kdim) h[tid] = 0;
  __syncthreads();
  int idx = blockIdx.x * 256 + tid;              // < B*N, block stays in one b
  int b = idx >> 14;                             // /16384
  float w = tanhf(logits[idx]);
  int kb = -1;
#pragma unroll
  for (int j = 0; j < Kdim; ++j) {
    float lo = -1.0f + 0.25f * (float)j;
    float hi = lo + 0.25f;
    if (w > lo && w <= hi && w != 0.0f) kb = j;
  }
  kbin[idx] = (signed char)kb;
  if (kb >= 0) atomicAdd(&h[kb], 1);
  __syncthreads();
  if (tid < Kdim) atomicAdd(&cnt[b * Kdim + tid], h[tid]);
}

// ---------------- kernel 2: per-(b,c) masked pooling + masked sum of squares ----
__global__ void __launch_bounds__(256) k_pool(const float* __restrict__ x,
                                              const signed char* __restrict__ kbin,
                                              float* __restrict__ pooled,
                                              float* __restrict__ sxx) {
  int bc = blockIdx.x;                 // b*C + c
  int b = bc >> 7;
  const float4* xr = (const float4*)(x + (size_t)bc * Ndim);
  const char4* kr = (const char4*)(kbin + b * Ndim);
  float acc[Kdim];
#pragma unroll
  for (int j = 0; j < Kdim; ++j) acc[j] = 0.f;
  float s2 = 0.f;
  int tid = threadIdx.x;
  for (int n4 = tid; n4 < Ndim / 4; n4 += 256) {
    float4 v = xr[n4];
    char4 kb = kr[n4];
    float ve[4] = {v.x, v.y, v.z, v.w};
    signed char ke[4] = {kb.x, kb.y, kb.z, kb.w};
#pragma unroll
    for (int e = 0; e < 4; ++e) {
      float xv = ve[e];
      int kv = ke[e];
      if (kv >= 0) s2 += xv * xv;
#pragma unroll
      for (int j = 0; j < Kdim; ++j) acc[j] += (kv == j) ? xv : 0.f;
    }
  }
#pragma unroll
  for (int off = 32; off > 0; off >>= 1) {
#pragma unroll
    for (int j = 0; j < Kdim; ++j) acc[j] += __shfl_down(acc[j], off);
    s2 += __shfl_down(s2, off);
  }
  __shared__ float red[4][Kdim + 1];
  int wv = tid >> 6, ln = tid & 63;
  if (ln == 0) {
#pragma unroll
    for (int j = 0; j < Kdim; ++j) red[wv][j] = acc[j];
    red[wv][Kdim] = s2;
  }
  __syncthreads();
  if (tid < Kdim) pooled[bc * Kdim + tid] = red[0][tid] + red[1][tid] + red[2][tid] + red[3][tid];
  if (tid == Kdim) sxx[bc] = red[0][Kdim] + red[1][Kdim] + red[2][Kdim] + red[3][Kdim];
}

// ---------------- kernel 2.5: warm bf16 W into every XCD's L2 ------------------
__global__ void __launch_bounds__(256) k_warm(const unsigned short* __restrict__ Wbf,
                                              float* __restrict__ dummy) {
  int g = blockIdx.x >> 3;   // 72 slices x 8 XCD copies
  int t = threadIdx.x;
  int idx = g * 256 + t;     // uint4 index into 9*16384 ushorts = 18432 uint4
  uint4 v = ((const uint4*)Wbf)[idx];
  float s = (float)(v.x ^ v.y ^ v.z ^ v.w);
#pragma unroll
  for (int off = 32; off > 0; off >>= 1) s += __shfl_down(s, off);
  if ((t & 63) == 0) dummy[blockIdx.x * 4 + (t >> 6)] = s;  // keep loads live
}

// ---------------- kernel 3: 3-layer transformer v8 (MFMA projections) ----------
__global__ void __launch_bounds__(1024) k_xform(
    const float* __restrict__ pooled, const int* __restrict__ cnt,
    const float* __restrict__ sxx, const unsigned short* __restrict__ Wbf,
    const float* __restrict__ ln_w, const float* __restrict__ ln_b,
    float* __restrict__ feat, float* __restrict__ mu_i, float* __restrict__ rs_i,
    float* __restrict__ ratio) {
  __shared__ float f_l[Kdim][132], q_l[Kdim][132], kk_l[Kdim][132], v_l[Kdim][132];
  __shared__ unsigned short fTh[16][132], fTl[16][132];  // B operand rows j (8 used)
  __shared__ float part[Kdim][Kdim][Cdim];
  __shared__ float pm[Kdim][Cdim], ps[Kdim][Cdim];
  __shared__ float lnw_l[Cdim], lnb_l[Cdim];
  __shared__ float cnt_raw[Kdim], cnt_div[Kdim];
  __shared__ float redA[Kdim][2], redB[Kdim][2];
  int b = blockIdx.x, tid = threadIdx.x;
  int c_ = tid & 127, h_ = tid >> 7;
  int o8 = tid >> 3, j8 = tid & 7;
  int wid = tid >> 6, lane = tid & 63;
  int l15 = lane & 15, lg = lane >> 4;
  const float inv_temp = 0.08838834764831845f;

  if (tid < Kdim) {
    int cc = cnt[b * Kdim + tid];
    cnt_raw[tid] = (float)cc;
    cnt_div[tid] = (float)(cc == 0 ? 1 : cc);
  }
  if (tid >= 128 && tid < 256) lnw_l[tid - 128] = ln_w[tid - 128];
  if (tid >= 256 && tid < 384) lnb_l[tid - 256] = ln_b[tid - 256];
  __syncthreads();
  {
    float fv = pooled[(b * Cdim + o8) * Kdim + j8] / cnt_div[j8];
    f_l[j8][o8] = fv;
    unsigned hi = rne16(fv);
    fTh[j8][o8] = (unsigned short)hi;
    fTl[j8][o8] = (unsigned short)rne16(fv - __uint_as_float(hi << 16));
  }
  float t_carry = 0.f;
  float sv[16];
  float mloc = 0.f;
  for (int layer = 0; layer < 3; ++layer) {
    if (layer > 0) {
      float S1 = redA[h_][0] + redA[h_][1];
      float S2 = redB[h_][0] + redB[h_][1];
      float mu = S1 * (1.f / Cdim);
      float var = S2 * (1.f / Cdim) - mu * mu;
      float rs = rsqrtf(var + 1e-6f);
      float fv = (t_carry - mu) * rs * lnw_l[c_] + lnb_l[c_];
      f_l[h_][c_] = fv;
      unsigned hi = rne16(fv);
      fTh[h_][c_] = (unsigned short)hi;
      fTl[h_][c_] = (unsigned short)rne16(fv - __uint_as_float(hi << 16));
    }
    __syncthreads();
    for (int job = wid; job < 24; job += 16) {
      int m = job >> 3, ot = job & 7;
      const unsigned short* A = Wbf + (size_t)(layer * 3 + m) * 16384 + (ot * 16 + l15) * 128;
      f32x4 acc = (f32x4){0.f, 0.f, 0.f, 0.f};
#pragma unroll
      for (int ks = 0; ks < 4; ++ks) {
        int kbase = ks * 32 + lg * 8;
        short8 a = *(const short8*)(A + kbase);
        short8 bh = *(const short8*)&fTh[l15][kbase];
        short8 bl = *(const short8*)&fTl[l15][kbase];
        acc = __builtin_amdgcn_mfma_f32_16x16x32_bf16(a, bh, acc, 0, 0, 0);
        acc = __builtin_amdgcn_mfma_f32_16x16x32_bf16(a, bl, acc, 0, 0, 0);
      }
      if (l15 < 8) {
#pragma unroll
        for (int r = 0; r < 4; ++r) {
          int o = ot * 16 + lg * 4 + r;
          float v = acc[r];
          if (m == 0) q_l[l15][o] = v * inv_temp;
          else if (m == 1) kk_l[l15][o] = v;
          else v_l[l15][o] = v;
        }
      }
    }
    __syncthreads();
    {
      int d0 = h_ * 16;
      float qv[8];
#pragma unroll
      for (int j = 0; j < 8; ++j) qv[j] = q_l[j][c_];
#pragma unroll
      for (int dd = 0; dd < 16; ++dd) sv[dd] = 0.f;
#pragma unroll
      for (int j = 0; j < 8; ++j) {
#pragma unroll
        for (int d4 = 0; d4 < 4; ++d4) {
          float4 k4 = *(const float4*)&kk_l[j][d0 + d4 * 4];
          sv[d4 * 4 + 0] = fmaf(qv[j], k4.x, sv[d4 * 4 + 0]);
          sv[d4 * 4 + 1] = fmaf(qv[j], k4.y, sv[d4 * 4 + 1]);
          sv[d4 * 4 + 2] = fmaf(qv[j], k4.z, sv[d4 * 4 + 2]);
          sv[d4 * 4 + 3] = fmaf(qv[j], k4.w, sv[d4 * 4 + 3]);
        }
      }
      mloc = sv[0];
#pragma unroll
      for (int dd = 1; dd < 16; ++dd) mloc = fmaxf(mloc, sv[dd]);
      float sl = 0.f;
#pragma unroll
      for (int dd = 0; dd < 16; ++dd) {
        sv[dd] = expf(sv[dd] - mloc);
        sl += sv[dd];
      }
      pm[h_][c_] = mloc;
      ps[h_][c_] = sl;
    }
    __syncthreads();
    {
      float M = pm[0][c_];
#pragma unroll
      for (int hh = 1; hh < 8; ++hh) M = fmaxf(M, pm[hh][c_]);
      float S = 0.f;
#pragma unroll
      for (int hh = 0; hh < 8; ++hh) S += ps[hh][c_] * expf(pm[hh][c_] - M);
      float fac = expf(mloc - M) / S;
#pragma unroll
      for (int dd = 0; dd < 16; ++dd) sv[dd] *= fac;
      int d0 = h_ * 16;
#pragma unroll
      for (int j = 0; j < 8; ++j) {
        float po = 0.f;
#pragma unroll
        for (int d4 = 0; d4 < 4; ++d4) {
          float4 v4 = *(const float4*)&v_l[j][d0 + d4 * 4];
          po = fmaf(sv[d4 * 4 + 0], v4.x, po);
          po = fmaf(sv[d4 * 4 + 1], v4.y, po);
          po = fmaf(sv[d4 * 4 + 2], v4.z, po);
          po = fmaf(sv[d4 * 4 + 3], v4.w, po);
        }
        part[h_][j][c_] = po;
      }
    }
    __syncthreads();
    {
      float t = f_l[h_][c_];
#pragma unroll
      for (int hh = 0; hh < 8; ++hh) t += part[hh][h_][c_];
      t_carry = t;
      float s1 = t, s2 = t * t;
#pragma unroll
      for (int off = 32; off > 0; off >>= 1) {
        s1 += __shfl_xor(s1, off);
        s2 += __shfl_xor(s2, off);
      }
      int wv = (tid >> 6) & 1;
      if ((tid & 63) == 0) { redA[h_][wv] = s1; redB[h_][wv] = s2; }
    }
    __syncthreads();
  }
  {
    float S1 = redA[h_][0] + redA[h_][1];
    float S2 = redB[h_][0] + redB[h_][1];
    float mu = S1 * (1.f / Cdim);
    float var = S2 * (1.f / Cdim) - mu * mu;
    float rs = rsqrtf(var + 1e-6f);
    f_l[h_][c_] = (t_carry - mu) * rs * lnw_l[c_] + lnb_l[c_];
  }
  __syncthreads();
  if (tid < Cdim) {
    int c = tid;
    float S1 = 0.f, S2c = 0.f;
#pragma unroll
    for (int j = 0; j < Kdim; ++j) {
      float pl = pooled[(b * Cdim + c) * Kdim + j];
      float fe = f_l[j][c];
      feat[(b * Cdim + c) * Kdim + j] = fe;
      S1 += pl + cnt_raw[j] * fe;
      S2c += 2.f * pl * fe + cnt_raw[j] * fe * fe;
    }
    float S2 = sxx[b * Cdim + c] + S2c;
    float mu = S1 * (1.f / Ndim);
    float var = S2 * (1.f / Ndim) - mu * mu;
    float rs = rsqrtf(var + 1e-5f);
    mu_i[b * Cdim + c] = mu;
    rs_i[b * Cdim + c] = rs;
    ratio[b * Cdim + c] = var * rs * rs;
  }
}

// ---------------- kernel 4: fold norms into per-(b,c) affine -------------------
__global__ void k_alpha(const float* __restrict__ mu_i, const float* __restrict__ rs_i,
                        const float* __restrict__ ratio, const float* __restrict__ bn_w,
                        const float* __restrict__ bn_b, float* __restrict__ alpha,
                        float* __restrict__ beta) {
  int c = threadIdx.x;
  float vb = 0.f;
  for (int b = 0; b < Bdim; ++b) vb += ratio[b * Cdim + c];
  vb *= (1.f / Bdim);
  float rsb = rsqrtf(vb + 1e-5f);
  float w = bn_w[c], bb = bn_b[c];
  for (int b = 0; b < Bdim; ++b) {
    float a = rs_i[b * Cdim + c] * rsb * w;
    alpha[b * Cdim + c] = a;
    beta[b * Cdim + c] = bb - mu_i[b * Cdim + c] * a;
  }
}

// ---------------- kernel 6: per-(b,c) mean of GELU'd activations (R1-proven) ---
__global__ void __launch_bounds__(256) k_gmean(
    const float* __restrict__ x, const signed char* __restrict__ kbin,
    const float* __restrict__ feat, const float* __restrict__ alpha,
    const float* __restrict__ beta, float* __restrict__ gmean) {
  int bc = blockIdx.x;
  int b = bc >> 7;
  __shared__ float fl[Kdim];
  int tid = threadIdx.x;
  if (tid < Kdim) fl[tid] = feat[bc * Kdim + tid];
  __syncthreads();
  float a = alpha[bc], be = beta[bc];
  const float4* xr = (const float4*)(x + (size_t)bc * Ndim);
  const char4* kr = (const char4*)(kbin + b * Ndim);
  float s = 0.f;
  for (int n4 = tid; n4 < Ndim / 4; n4 += 256) {
    float4 v = xr[n4];
    char4 kb = kr[n4];
    float ve[4] = {v.x, v.y, v.z, v.w};
    signed char ke[4] = {kb.x, kb.y, kb.z, kb.w};
#pragma unroll
    for (int e = 0; e < 4; ++e) {
      int kv = ke[e];
      float rec = 0.f;
#pragma unroll
      for (int j = 0; j < Kdim; ++j) rec += (kv == j) ? (ve[e] + fl[j]) : 0.f;
      float h = fmaf(a, rec, be);
      s += 0.5f * h * (1.0f + erff(h * 0.7071067811865475244f));
    }
  }
#pragma unroll
  for (int off = 32; off > 0; off >>= 1) s += __shfl_down(s, off);
  __shared__ float red[4];
  int wv = tid >> 6;
  if ((tid & 63) == 0) red[wv] = s;
  __syncthreads();
  if (tid == 0) gmean[bc] = (red[0] + red[1] + red[2] + red[3]) * (1.0f / Ndim);
}

// ---------------- kernel 7: SE MLP from gmean (linearity) ----------------------
__global__ void __launch_bounds__(128) k_mlp(const float* __restrict__ gmean,
                                             const float* __restrict__ W,      // conv0_w [o][c]
                                             const float* __restrict__ conv_b,
                                             const float* __restrict__ fc1w,
                                             const float* __restrict__ fc1b,
                                             const float* __restrict__ fc2w,
                                             const float* __restrict__ fc2b,
                                             float* __restrict__ f2g) {
  __shared__ float gm[Cdim];
  __shared__ float sq[Cdim];
  __shared__ float f1[64];
  int b = blockIdx.x, tid = threadIdx.x;
  gm[tid] = gmean[b * Cdim + tid];
  __syncthreads();
  float a = conv_b[tid];
  const float* wr = W + tid * Cdim;
  for (int c = 0; c < Cdim; ++c) a = fmaf(wr[c], gm[c], a);
  sq[tid] = a;
  __syncthreads();
  if (tid < 64) {
    float a1 = fc1b[tid];
    for (int c = 0; c < Cdim; ++c) a1 = fmaf(fc1w[tid * Cdim + c], sq[c], a1);
    f1[tid] = 0.5f * a1 * (1.0f + erff(a1 * 0.7071067811865475244f));
  }
  __syncthreads();
  float a2 = fc2b[tid];
  for (int i = 0; i < 64; ++i) a2 = fmaf(fc2w[tid * 64 + i], f1[i], a2);
  f2g[b * Cdim + tid] = 1.0f / (1.0f + expf(-a2));
}

// ---------------- kernel 8: fused recon+gelu + pipelined multi-tile MFMA GEMM --
// R12 skeleton (W-in-LDS swizzled, 2 barriers/tile, T14 reg-staged next tile),
// B-stage = x->gelu->bf16 LDS [c][132] (no gpack round-trip). B-frag = 8 scalar
// ds_read_u16 column reads: bank (2c+n/2)%32 -> 16 lanes / 8 banks = 2-way free.
__global__ void __launch_bounds__(1024) k_convf(
    const float* __restrict__ x, const signed char* __restrict__ kbin,
    const float* __restrict__ feat, const float* __restrict__ alpha,
    const float* __restrict__ beta,
    const unsigned short* __restrict__ Whs, const unsigned short* __restrict__ Wls,
    const float* __restrict__ bias, const float* __restrict__ f2g,
    float* __restrict__ out) {
  __shared__ unsigned short Whl[16384];       // 32KB swizzled
  __shared__ unsigned short Wll[16384];       // 32KB swizzled
  __shared__ unsigned short Bg[2][Cdim][132]; // 2x33.8KB bf16 [c][n]
  __shared__ float feat_l[Cdim][Kdim];
  __shared__ float al_l[Cdim], be_l[Cdim], bi_l[Cdim], f2_l[Cdim];
  int t = threadIdx.x;
  int blk = blockIdx.x;
  int b = blk >> 5;            // 32 blocks per b, 4 tiles each
  int tile0 = blk * 4;
  // ---- prologue: W->LDS, feat/affine, stage tile0 ----
  {
    const uint4* gw = (const uint4*)Whs;
    const uint4* gl = (const uint4*)Wls;
    ((uint4*)Whl)[t] = gw[t];
    ((uint4*)Whl)[t + 1024] = gw[t + 1024];
    ((uint4*)Wll)[t] = gl[t];
    ((uint4*)Wll)[t + 1024] = gl[t + 1024];
  }
  ((float*)feat_l)[t] = feat[b * Cdim * Kdim + t];
  if (t < 128) {
    al_l[t] = alpha[b * Cdim + t];
    be_l[t] = beta[b * Cdim + t];
    bi_l[t] = bias[t];
    f2_l[t] = f2g[b * Cdim + t];
  }
  int q = t & 31;               // same q for all 4 sub-rows (1024%32==0)
  int c0 = t >> 5;              // rows c0, c0+32, c0+64, c0+96
  float4 xv[4];
  char4 kc;
  {
    int nb = tile0 & 127;
#pragma unroll
    for (int i = 0; i < 4; ++i)
      xv[i] = *(const float4*)(x + ((size_t)(b * Cdim + c0 + i * 32)) * Ndim + nb * 128 + q * 4);
    kc = *(const char4*)(kbin + b * Ndim + nb * 128 + q * 4);
  }
  __syncthreads();  // al/be/feat visible for gelu
  // gelu tile0 -> Bg[0]
  {
#pragma unroll
    for (int i = 0; i < 4; ++i) {
      int c = c0 + i * 32;
      float a = al_l[c], be = be_l[c];
      float xe[4] = {xv[i].x, xv[i].y, xv[i].z, xv[i].w};
      signed char ke[4] = {kc.x, kc.y, kc.z, kc.w};
      unsigned short rr[4];
#pragma unroll
      for (int e = 0; e < 4; ++e) {
        float rec = (ke[e] >= 0) ? (xe[e] + feat_l[c][ke[e]]) : 0.0f;
        float h = fmaf(a, rec, be);
        float g = 0.5f * h * (1.0f + erff(h * 0.7071067811865475244f));
        rr[e] = (unsigned short)rne16(g);
      }
      *(ushort4*)&Bg[0][c][q * 4] = make_ushort4(rr[0], rr[1], rr[2], rr[3]);
    }
  }
  __syncthreads();  // Bg[0] + W ready
  int w = t >> 6, lane = t & 63;
  int wo = (w & 1) * 64, wn = (w >> 1) * 16;  // 2 o-halves x 8 n-groups
  int l15 = lane & 15, lg = lane >> 4;
  int nrow = wn + l15;
  int cur = 0;
  for (int tt = 0; tt < 4; ++tt) {
    // T14: issue next tile's loads before compute
    if (tt < 3) {
      int nb = (tile0 + tt + 1) & 127;
#pragma unroll
      for (int i = 0; i < 4; ++i)
        xv[i] = *(const float4*)(x + ((size_t)(b * Cdim + c0 + i * 32)) * Ndim + nb * 128 + q * 4);
      kc = *(const char4*)(kbin + b * Ndim + nb * 128 + q * 4);
    }
    // MFMA over Bg[cur]
    f32x4 acc[4];
#pragma unroll
    for (int of = 0; of < 4; ++of) acc[of] = (f32x4){0.f, 0.f, 0.f, 0.f};
#pragma unroll
    for (int kb = 0; kb < 4; ++kb) {
      int g = kb * 4 + lg;
      int kbase = g * 8;
      short8 bb;
#pragma unroll
      for (int j = 0; j < 8; ++j) bb[j] = (short)Bg[cur][kbase + j][nrow];
#pragma unroll
      for (int of = 0; of < 4; ++of) {
        int o = wo + of * 16 + l15;
        int apos = o * 128 + ((g ^ (o & 7)) << 3);
        short8 ah = *(const short8*)&Whl[apos];
        short8 al_ = *(const short8*)&Wll[apos];
        acc[of] = __builtin_amdgcn_mfma_f32_16x16x32_bf16(ah, bb, acc[of], 0, 0, 0);
        acc[of] = __builtin_amdgcn_mfma_f32_16x16x32_bf16(al_, bb, acc[of], 0, 0, 0);
      }
    }
    __syncthreads();
    // gelu + write next tile into Bg[cur^1]
    if (tt < 3) {
#pragma unroll
      for (int i = 0; i < 4; ++i) {
        int c = c0 + i * 32;
        float a = al_l[c], be = be_l[c];
        float xe[4] = {xv[i].x, xv[i].y, xv[i].z, xv[i].w};
        signed char ke[4] = {kc.x, kc.y, kc.z, kc.w};
        unsigned short rr[4];
#pragma unroll
        for (int e = 0; e < 4; ++e) {
          float rec = (ke[e] >= 0) ? (xe[e] + feat_l[c][ke[e]]) : 0.0f;
          float h = fmaf(a, rec, be);
          float g = 0.5f * h * (1.0f + erff(h * 0.7071067811865475244f));
          rr[e] = (unsigned short)rne16(g);
        }
        *(ushort4*)&Bg[cur ^ 1][c][q * 4] = make_ushort4(rr[0], rr[1], rr[2], rr[3]);
      }
    }
    __syncthreads();
    // epilogue store tile tt (drains under next tile's compute)
    int n0 = ((tile0 + tt) & 127) * 128;
#pragma unroll
    for (int of = 0; of < 4; ++of) {
#pragma unroll
      for (int r = 0; r < 4; ++r) {
        int o = wo + of * 16 + lg * 4 + r;
        out[((size_t)(b * Cdim + o)) * Ndim + n0 + wn + l15] =
            (acc[of][r] + bi_l[o]) * f2_l[o];
      }
    }
    cur ^= 1;
  }
}

extern "C" void kernel_launch(void* const* d_in, const int* in_sizes, int n_in,
                              void* d_out, int out_size, void* d_ws, size_t ws_size,
                              hipStream_t stream) {
  const float* x = (const float*)d_in[0];
  const float* logits = (const float*)d_in[1];
  const float* Wq1 = (const float*)d_in[2];
  const float* Wk1 = (const float*)d_in[3];
  const float* Wv1 = (const float*)d_in[4];
  const float* Wq2 = (const float*)d_in[5];
  const float* Wk2 = (const float*)d_in[6];
  const float* Wv2 = (const float*)d_in[7];
  const float* Wq3 = (const float*)d_in[8];
  const float* Wk3 = (const float*)d_in[9];
  const float* Wv3 = (const float*)d_in[10];
  const float* ln_w = (const float*)d_in[11];
  const float* ln_b = (const float*)d_in[12];
  const float* conv0_w = (const float*)d_in[13];
  const float* conv0_b = (const float*)d_in[14];
  const float* bn_w = (const float*)d_in[15];
  const float* bn_b = (const float*)d_in[16];
  const float* fc1_w = (const float*)d_in[17];
  const float* fc1_b = (const float*)d_in[18];
  const float* fc2_w = (const float*)d_in[19];
  const float* fc2_b = (const float*)d_in[20];
  float* out = (float*)d_out;

  char* p = (char*)d_ws;
  auto alloc = [&](size_t bytes) {
    char* r = p;
    p += (bytes + 255) & ~(size_t)255;
    return r;
  };
  signed char* kbin = (signed char*)alloc(Bdim * Ndim);
  int* cnt = (int*)alloc(Bdim * Kdim * 4);
  float* pooled = (float*)alloc(Bdim * Cdim * Kdim * 4);
  float* sxx = (float*)alloc(Bdim * Cdim * 4);
  float* feat = (float*)alloc(Bdim * Cdim * Kdim * 4);
  float* mu_i = (float*)alloc(Bdim * Cdim * 4);
  float* rs_i = (float*)alloc(Bdim * Cdim * 4);
  float* ratio = (float*)alloc(Bdim * Cdim * 4);
  float* alpha = (float*)alloc(Bdim * Cdim * 4);
  float* beta = (float*)alloc(Bdim * Cdim * 4);
  unsigned short* Whs = (unsigned short*)alloc(Cdim * Cdim * 2);
  unsigned short* Wls = (unsigned short*)alloc(Cdim * Cdim * 2);
  unsigned short* Wbf = (unsigned short*)alloc(9 * Cdim * Cdim * 2);  // 288KB bf16
  float* f2g = (float*)alloc(Bdim * Cdim * 4);
  float* gmean = (float*)alloc(Bdim * Cdim * 4);
  float* warmdummy = (float*)alloc(576 * 4 * 4);
  (void)ws_size;

  k_prep<<<640, 256, 0, stream>>>(conv0_w, Whs, Wls,
                                  Wq1, Wk1, Wv1, Wq2, Wk2, Wv2, Wq3, Wk3, Wv3,
                                  Wbf, cnt);
  k_bin<<<Bdim * Ndim / 256, 256, 0, stream>>>(logits, kbin, cnt);
  k_pool<<<Bdim * Cdim, 256, 0, stream>>>(x, kbin, pooled, sxx);
  // warm bf16 W into every XCD's L2 AFTER k_pool's 67MB stream evicted it
  k_warm<<<576, 256, 0, stream>>>(Wbf, warmdummy);
  k_xform<<<Bdim, 1024, 0, stream>>>(pooled, cnt, sxx, Wbf, ln_w, ln_b,
                                     feat, mu_i, rs_i, ratio);
  k_alpha<<<1, 128, 0, stream>>>(mu_i, rs_i, ratio, bn_w, bn_b, alpha, beta);
  k_gmean<<<Bdim * Cdim, 256, 0, stream>>>(x, kbin, feat, alpha, beta, gmean);
  k_mlp<<<Bdim, 128, 0, stream>>>(gmean, conv0_w, conv0_b, fc1_w, fc1_b, fc2_w, fc2_b, f2g);
  k_convf<<<256, 1024, 0, stream>>>(x, kbin, feat, alpha, beta, Whs, Wls,
                                    conv0_b, f2g, out);
}

// Round 18
// 120.778 us; speedup vs baseline: 1.1105x; 1.1105x over previous
//
#include <hip/hip_runtime.h>
#include <math.h>

#define Bdim 8
#define Cdim 128
#define Ndim 16384
#define Kdim 8

typedef __attribute__((ext_vector_type(8))) short short8;
typedef __attribute__((ext_vector_type(4))) float f32x4;

__device__ __forceinline__ unsigned rne16(float x) {
  unsigned u = __float_as_uint(x);
  return (u + 0x7FFFu + ((u >> 16) & 1u)) >> 16;
}

// ---------------- kernel 0: merged prep (wsplit + wprep + zero cnt/gmean) ------
__global__ void __launch_bounds__(256) k_prep(
    const float* __restrict__ W, unsigned short* __restrict__ Wh,
    unsigned short* __restrict__ Wl, unsigned short* __restrict__ Whs,
    unsigned short* __restrict__ Wls,
    const float* __restrict__ p0, const float* __restrict__ p1, const float* __restrict__ p2,
    const float* __restrict__ p3, const float* __restrict__ p4, const float* __restrict__ p5,
    const float* __restrict__ p6, const float* __restrict__ p7, const float* __restrict__ p8,
    unsigned short* __restrict__ Wbf, int* __restrict__ cnt, float* __restrict__ gmean) {
  int blk = blockIdx.x, t = threadIdx.x;
  if (blk < 64) {
    int idx = blk * 256 + t;  // 16384, [o][c] row-major
    int o = idx >> 7, c = idx & 127;
    float v = W[idx];
    unsigned u = __float_as_uint(v);
    unsigned rh = (u + 0x7FFFu + ((u >> 16) & 1u)) & 0xFFFF0000u;
    float vh = __uint_as_float(rh);
    float r = v - vh;  // exact
    unsigned u2 = __float_as_uint(r);
    unsigned rl = (u2 + 0x7FFFu + ((u2 >> 16) & 1u)) >> 16;
    unsigned short hs = (unsigned short)(rh >> 16);
    unsigned short ls = (unsigned short)rl;
    Wh[idx] = hs;
    Wl[idx] = ls;
    int pos = o * 128 + (((c >> 3) ^ (o & 7)) << 3) + (c & 7);
    Whs[pos] = hs;
    Wls[pos] = ls;
    if (blk == 0 && t < Bdim * Kdim) cnt[t] = 0;
    if (blk < 4) gmean[blk * 256 + t] = 0.f;
  } else {
    int m = (blk - 64) >> 6;                 // 9 matrices x 64 blocks
    int i = ((blk - 64) & 63) * 256 + t;
    const float* mp = m == 0 ? p0 : m == 1 ? p1 : m == 2 ? p2 : m == 3 ? p3 : m == 4 ? p4
                    : m == 5 ? p5 : m == 6 ? p6 : m == 7 ? p7 : p8;
    Wbf[m * 16384 + i] = (unsigned short)rne16(mp[i]);
  }
}

// ---------------- kernel 1: bin assignment + counts ----------------
__global__ void __launch_bounds__(256) k_bin(const float* __restrict__ logits,
                                             signed char* __restrict__ kbin,
                                             int* __restrict__ cnt) {
  __shared__ int h[Kdim];
  int tid = threadIdx.x;
  if (tid < Kdim) h[tid] = 0;
  __syncthreads();
  int idx = blockIdx.x * 256 + tid;              // < B*N, block stays in one b
  int b = idx >> 14;                             // /16384
  float w = tanhf(logits[idx]);
  int kb = -1;
#pragma unroll
  for (int j = 0; j < Kdim; ++j) {
    float lo = -1.0f + 0.25f * (float)j;
    float hi = lo + 0.25f;
    if (w > lo && w <= hi && w != 0.0f) kb = j;
  }
  kbin[idx] = (signed char)kb;
  if (kb >= 0) atomicAdd(&h[kb], 1);
  __syncthreads();
  if (tid < Kdim) atomicAdd(&cnt[b * Kdim + tid], h[tid]);
}

// ---------------- kernel 2: per-(b,c) masked pooling + masked sum of squares ----
__global__ void __launch_bounds__(256) k_pool(const float* __restrict__ x,
                                              const signed char* __restrict__ kbin,
                                              float* __restrict__ pooled,
                                              float* __restrict__ sxx) {
  int bc = blockIdx.x;                 // b*C + c
  int b = bc >> 7;
  const float4* xr = (const float4*)(x + (size_t)bc * Ndim);
  const char4* kr = (const char4*)(kbin + b * Ndim);
  float acc[Kdim];
#pragma unroll
  for (int j = 0; j < Kdim; ++j) acc[j] = 0.f;
  float s2 = 0.f;
  int tid = threadIdx.x;
  for (int n4 = tid; n4 < Ndim / 4; n4 += 256) {
    float4 v = xr[n4];
    char4 kb = kr[n4];
    float ve[4] = {v.x, v.y, v.z, v.w};
    signed char ke[4] = {kb.x, kb.y, kb.z, kb.w};
#pragma unroll
    for (int e = 0; e < 4; ++e) {
      float xv = ve[e];
      int kv = ke[e];
      if (kv >= 0) s2 += xv * xv;
#pragma unroll
      for (int j = 0; j < Kdim; ++j) acc[j] += (kv == j) ? xv : 0.f;
    }
  }
#pragma unroll
  for (int off = 32; off > 0; off >>= 1) {
#pragma unroll
    for (int j = 0; j < Kdim; ++j) acc[j] += __shfl_down(acc[j], off);
    s2 += __shfl_down(s2, off);
  }
  __shared__ float red[4][Kdim + 1];
  int wv = tid >> 6, ln = tid & 63;
  if (ln == 0) {
#pragma unroll
    for (int j = 0; j < Kdim; ++j) red[wv][j] = acc[j];
    red[wv][Kdim] = s2;
  }
  __syncthreads();
  if (tid < Kdim) pooled[bc * Kdim + tid] = red[0][tid] + red[1][tid] + red[2][tid] + red[3][tid];
  if (tid == Kdim) sxx[bc] = red[0][Kdim] + red[1][Kdim] + red[2][Kdim] + red[3][Kdim];
}

// ---------------- kernel 2.5: warm bf16 W into every XCD's L2 ------------------
__global__ void __launch_bounds__(256) k_warm(const unsigned short* __restrict__ Wbf,
                                              float* __restrict__ dummy) {
  int g = blockIdx.x >> 3;   // 72 slices x 8 XCD copies
  int t = threadIdx.x;
  int idx = g * 256 + t;     // uint4 index into 9*16384 ushorts = 18432 uint4
  uint4 v = ((const uint4*)Wbf)[idx];
  float s = (float)(v.x ^ v.y ^ v.z ^ v.w);
#pragma unroll
  for (int off = 32; off > 0; off >>= 1) s += __shfl_down(s, off);
  if ((t & 63) == 0) dummy[blockIdx.x * 4 + (t >> 6)] = s;  // keep loads live
}

// ---------------- kernel 3: 3-layer transformer v8 (MFMA projections) ----------
__global__ void __launch_bounds__(1024) k_xform(
    const float* __restrict__ pooled, const int* __restrict__ cnt,
    const float* __restrict__ sxx, const unsigned short* __restrict__ Wbf,
    const float* __restrict__ ln_w, const float* __restrict__ ln_b,
    float* __restrict__ feat, float* __restrict__ mu_i, float* __restrict__ rs_i,
    float* __restrict__ ratio) {
  __shared__ float f_l[Kdim][132], q_l[Kdim][132], kk_l[Kdim][132], v_l[Kdim][132];
  __shared__ unsigned short fTh[16][132], fTl[16][132];  // B operand rows j (8 used)
  __shared__ float part[Kdim][Kdim][Cdim];
  __shared__ float pm[Kdim][Cdim], ps[Kdim][Cdim];
  __shared__ float lnw_l[Cdim], lnb_l[Cdim];
  __shared__ float cnt_raw[Kdim], cnt_div[Kdim];
  __shared__ float redA[Kdim][2], redB[Kdim][2];
  int b = blockIdx.x, tid = threadIdx.x;
  int c_ = tid & 127, h_ = tid >> 7;
  int o8 = tid >> 3, j8 = tid & 7;
  int wid = tid >> 6, lane = tid & 63;
  int l15 = lane & 15, lg = lane >> 4;
  const float inv_temp = 0.08838834764831845f;

  if (tid < Kdim) {
    int cc = cnt[b * Kdim + tid];
    cnt_raw[tid] = (float)cc;
    cnt_div[tid] = (float)(cc == 0 ? 1 : cc);
  }
  if (tid >= 128 && tid < 256) lnw_l[tid - 128] = ln_w[tid - 128];
  if (tid >= 256 && tid < 384) lnb_l[tid - 256] = ln_b[tid - 256];
  __syncthreads();
  {
    float fv = pooled[(b * Cdim + o8) * Kdim + j8] / cnt_div[j8];
    f_l[j8][o8] = fv;
    unsigned hi = rne16(fv);
    fTh[j8][o8] = (unsigned short)hi;
    fTl[j8][o8] = (unsigned short)rne16(fv - __uint_as_float(hi << 16));
  }
  float t_carry = 0.f;
  float sv[16];
  float mloc = 0.f;
  for (int layer = 0; layer < 3; ++layer) {
    // ---- s1: LN-finish (layer>0) writes f_l + fT ----
    if (layer > 0) {
      float S1 = redA[h_][0] + redA[h_][1];
      float S2 = redB[h_][0] + redB[h_][1];
      float mu = S1 * (1.f / Cdim);
      float var = S2 * (1.f / Cdim) - mu * mu;
      float rs = rsqrtf(var + 1e-6f);
      float fv = (t_carry - mu) * rs * lnw_l[c_] + lnb_l[c_];
      f_l[h_][c_] = fv;
      unsigned hi = rne16(fv);
      fTh[h_][c_] = (unsigned short)hi;
      fTl[h_][c_] = (unsigned short)rne16(fv - __uint_as_float(hi << 16));
    }
    __syncthreads();
    // ---- s2: MFMA projections (24 jobs over 16 waves) ----
    for (int job = wid; job < 24; job += 16) {
      int m = job >> 3, ot = job & 7;
      const unsigned short* A = Wbf + (size_t)(layer * 3 + m) * 16384 + (ot * 16 + l15) * 128;
      f32x4 acc = (f32x4){0.f, 0.f, 0.f, 0.f};
#pragma unroll
      for (int ks = 0; ks < 4; ++ks) {
        int kbase = ks * 32 + lg * 8;
        short8 a = *(const short8*)(A + kbase);
        short8 bh = *(const short8*)&fTh[l15][kbase];
        short8 bl = *(const short8*)&fTl[l15][kbase];
        acc = __builtin_amdgcn_mfma_f32_16x16x32_bf16(a, bh, acc, 0, 0, 0);
        acc = __builtin_amdgcn_mfma_f32_16x16x32_bf16(a, bl, acc, 0, 0, 0);
      }
      if (l15 < 8) {
#pragma unroll
        for (int r = 0; r < 4; ++r) {
          int o = ot * 16 + lg * 4 + r;
          float v = acc[r];
          if (m == 0) q_l[l15][o] = v * inv_temp;
          else if (m == 1) kk_l[l15][o] = v;
          else v_l[l15][o] = v;
        }
      }
    }
    __syncthreads();
    // ---- s3: local scores + local max/expsum (online softmax) ----
    {
      int d0 = h_ * 16;
      float qv[8];
#pragma unroll
      for (int j = 0; j < 8; ++j) qv[j] = q_l[j][c_];  // lane-consecutive
#pragma unroll
      for (int dd = 0; dd < 16; ++dd) sv[dd] = 0.f;
#pragma unroll
      for (int j = 0; j < 8; ++j) {
#pragma unroll
        for (int d4 = 0; d4 < 4; ++d4) {
          float4 k4 = *(const float4*)&kk_l[j][d0 + d4 * 4];  // broadcast
          sv[d4 * 4 + 0] = fmaf(qv[j], k4.x, sv[d4 * 4 + 0]);
          sv[d4 * 4 + 1] = fmaf(qv[j], k4.y, sv[d4 * 4 + 1]);
          sv[d4 * 4 + 2] = fmaf(qv[j], k4.z, sv[d4 * 4 + 2]);
          sv[d4 * 4 + 3] = fmaf(qv[j], k4.w, sv[d4 * 4 + 3]);
        }
      }
      mloc = sv[0];
#pragma unroll
      for (int dd = 1; dd < 16; ++dd) mloc = fmaxf(mloc, sv[dd]);
      float sl = 0.f;
#pragma unroll
      for (int dd = 0; dd < 16; ++dd) {
        sv[dd] = expf(sv[dd] - mloc);
        sl += sv[dd];
      }
      pm[h_][c_] = mloc;
      ps[h_][c_] = sl;
    }
    __syncthreads();
    // ---- s4: global softmax rescale + PV partials ----
    {
      float M = pm[0][c_];
#pragma unroll
      for (int hh = 1; hh < 8; ++hh) M = fmaxf(M, pm[hh][c_]);
      float S = 0.f;
#pragma unroll
      for (int hh = 0; hh < 8; ++hh) S += ps[hh][c_] * expf(pm[hh][c_] - M);
      float fac = expf(mloc - M) / S;
#pragma unroll
      for (int dd = 0; dd < 16; ++dd) sv[dd] *= fac;
      int d0 = h_ * 16;
#pragma unroll
      for (int j = 0; j < 8; ++j) {
        float po = 0.f;
#pragma unroll
        for (int d4 = 0; d4 < 4; ++d4) {
          float4 v4 = *(const float4*)&v_l[j][d0 + d4 * 4];  // broadcast
          po = fmaf(sv[d4 * 4 + 0], v4.x, po);
          po = fmaf(sv[d4 * 4 + 1], v4.y, po);
          po = fmaf(sv[d4 * 4 + 2], v4.z, po);
          po = fmaf(sv[d4 * 4 + 3], v4.w, po);
        }
        part[h_][j][c_] = po;  // lane-consecutive
      }
    }
    __syncthreads();
    // ---- s5: combine partials + residual + LN reduce ----
    {
      float t = f_l[h_][c_];
#pragma unroll
      for (int hh = 0; hh < 8; ++hh) t += part[hh][h_][c_];
      t_carry = t;
      float s1 = t, s2 = t * t;
#pragma unroll
      for (int off = 32; off > 0; off >>= 1) {
        s1 += __shfl_xor(s1, off);
        s2 += __shfl_xor(s2, off);
      }
      int wv = (tid >> 6) & 1;
      if ((tid & 63) == 0) { redA[h_][wv] = s1; redB[h_][wv] = s2; }
    }
    __syncthreads();
  }
  // ---- epilogue LN-finish ----
  {
    float S1 = redA[h_][0] + redA[h_][1];
    float S2 = redB[h_][0] + redB[h_][1];
    float mu = S1 * (1.f / Cdim);
    float var = S2 * (1.f / Cdim) - mu * mu;
    float rs = rsqrtf(var + 1e-6f);
    f_l[h_][c_] = (t_carry - mu) * rs * lnw_l[c_] + lnb_l[c_];
  }
  __syncthreads();
  // ---- closed-form instance-norm stats ----
  if (tid < Cdim) {
    int c = tid;
    float S1 = 0.f, S2c = 0.f;
#pragma unroll
    for (int j = 0; j < Kdim; ++j) {
      float pl = pooled[(b * Cdim + c) * Kdim + j];
      float fe = f_l[j][c];
      feat[(b * Cdim + c) * Kdim + j] = fe;
      S1 += pl + cnt_raw[j] * fe;
      S2c += 2.f * pl * fe + cnt_raw[j] * fe * fe;
    }
    float S2 = sxx[b * Cdim + c] + S2c;
    float mu = S1 * (1.f / Ndim);
    float var = S2 * (1.f / Ndim) - mu * mu;
    float rs = rsqrtf(var + 1e-5f);
    mu_i[b * Cdim + c] = mu;
    rs_i[b * Cdim + c] = rs;
    ratio[b * Cdim + c] = var * rs * rs;
  }
}

// ---------------- kernel 4: fold norms into affine (fallback path only) --------
__global__ void k_alpha(const float* __restrict__ mu_i, const float* __restrict__ rs_i,
                        const float* __restrict__ ratio, const float* __restrict__ bn_w,
                        const float* __restrict__ bn_b, float* __restrict__ alpha,
                        float* __restrict__ beta) {
  int c = threadIdx.x;
  float vb = 0.f;
  for (int b = 0; b < Bdim; ++b) vb += ratio[b * Cdim + c];
  vb *= (1.f / Bdim);
  float rsb = rsqrtf(vb + 1e-5f);
  float w = bn_w[c], bb = bn_b[c];
  for (int b = 0; b < Bdim; ++b) {
    float a = rs_i[b * Cdim + c] * rsb * w;
    alpha[b * Cdim + c] = a;
    beta[b * Cdim + c] = bb - mu_i[b * Cdim + c] * a;
  }
}

// ---------------- kernel 6a: gelu once -> transposed swizzled bf16 tiles -------
// (R14-proven version: erff, phase3b LDS column sums, one atomic per (c,half))
__global__ void __launch_bounds__(256) k_gpack(
    const float* __restrict__ x, const signed char* __restrict__ kbin,
    const float* __restrict__ feat,
    const float* __restrict__ mu_i, const float* __restrict__ rs_i,
    const float* __restrict__ ratio, const float* __restrict__ bn_w,
    const float* __restrict__ bn_b, unsigned short* __restrict__ gpack,
    float* __restrict__ gsum) {
  __shared__ unsigned short xg[Cdim][132];   // [c][n] bf16 (33.8KB)
  __shared__ float feat_l[Cdim][Kdim];
  __shared__ float al_l[Cdim], be_l[Cdim];
  __shared__ signed char kb_l[128];
  int tile = blockIdx.x;
  int b = tile >> 7, nb = tile & 127;
  int n0 = nb * 128;
  int t = threadIdx.x;
  for (int idx = t; idx < Cdim * Kdim; idx += 256)
    ((float*)feat_l)[idx] = feat[b * Cdim * Kdim + idx];
  if (t < 128) {
    int c = t;
    float vb = 0.f;
#pragma unroll
    for (int bb = 0; bb < Bdim; ++bb) vb += ratio[bb * Cdim + c];
    vb *= (1.f / Bdim);
    float rsb = rsqrtf(vb + 1e-5f);
    float a = rs_i[b * Cdim + c] * rsb * bn_w[c];
    al_l[c] = a;
    be_l[c] = bn_b[c] - mu_i[b * Cdim + c] * a;
    kb_l[c] = kbin[b * Ndim + n0 + c];
  }
  __syncthreads();
#pragma unroll 4
  for (int it = 0; it < 16; ++it) {
    int idx = it * 256 + t;
    int q = idx & 31, c = idx >> 5;
    float4 xv = *(const float4*)(x + ((size_t)(b * Cdim + c)) * Ndim + n0 + q * 4);
    float a = al_l[c], be = be_l[c];
    float xe[4] = {xv.x, xv.y, xv.z, xv.w};
    unsigned short rr[4];
#pragma unroll
    for (int e = 0; e < 4; ++e) {
      int kb = kb_l[q * 4 + e];
      float rec = (kb >= 0) ? (xe[e] + feat_l[c][kb]) : 0.0f;
      float h = fmaf(a, rec, be);
      float g = 0.5f * h * (1.0f + erff(h * 0.7071067811865475244f));
      rr[e] = (unsigned short)rne16(g);
    }
    *(ushort4*)&xg[c][q * 4] = make_ushort4(rr[0], rr[1], rr[2], rr[3]);
  }
  __syncthreads();
  {
    int c = t >> 1, half = t & 1;
    float s = 0.f;
#pragma unroll 8
    for (int i = 0; i < 64; ++i) {
      unsigned us = xg[c][half * 64 + i];
      s += __uint_as_float(us << 16);
    }
    s += __shfl_xor(s, 1);
    if (half == 0) atomicAdd(&gsum[b * Cdim + c], s);
  }
  unsigned short* tb = gpack + (size_t)tile * 16384;
#pragma unroll 2
  for (int it = 0; it < 8; ++it) {
    int idx = it * 256 + t;
    int cg = idx & 15, n = idx >> 4;
    unsigned u32s[4];
#pragma unroll
    for (int p = 0; p < 4; ++p) {
      unsigned lo = xg[cg * 8 + 2 * p][n];
      unsigned hi = xg[cg * 8 + 2 * p + 1][n];
      u32s[p] = lo | (hi << 16);
    }
    int g = cg ^ (n & 7);
    *(uint4*)(tb + n * 128 + g * 8) = make_uint4(u32s[0], u32s[1], u32s[2], u32s[3]);
  }
}

// ---------------- kernel 6b (fallback): per-(b,c) mean of GELU'd activations ---
__global__ void __launch_bounds__(256) k_gmean(
    const float* __restrict__ x, const signed char* __restrict__ kbin,
    const float* __restrict__ feat, const float* __restrict__ alpha,
    const float* __restrict__ beta, float* __restrict__ gmean) {
  int bc = blockIdx.x;
  int b = bc >> 7;
  __shared__ float fl[Kdim];
  int tid = threadIdx.x;
  if (tid < Kdim) fl[tid] = feat[bc * Kdim + tid];
  __syncthreads();
  float a = alpha[bc], be = beta[bc];
  const float4* xr = (const float4*)(x + (size_t)bc * Ndim);
  const char4* kr = (const char4*)(kbin + b * Ndim);
  float s = 0.f;
  for (int n4 = tid; n4 < Ndim / 4; n4 += 256) {
    float4 v = xr[n4];
    char4 kb = kr[n4];
    float ve[4] = {v.x, v.y, v.z, v.w};
    signed char ke[4] = {kb.x, kb.y, kb.z, kb.w};
#pragma unroll
    for (int e = 0; e < 4; ++e) {
      int kv = ke[e];
      float rec = 0.f;
#pragma unroll
      for (int j = 0; j < Kdim; ++j) rec += (kv == j) ? (ve[e] + fl[j]) : 0.f;
      float h = fmaf(a, rec, be);
      s += 0.5f * h * (1.0f + erff(h * 0.7071067811865475244f));
    }
  }
#pragma unroll
  for (int off = 32; off > 0; off >>= 1) s += __shfl_down(s, off);
  __shared__ float red[4];
  int wv = tid >> 6;
  if ((tid & 63) == 0) red[wv] = s;
  __syncthreads();
  if (tid == 0) gmean[bc] = (red[0] + red[1] + red[2] + red[3]) * (1.0f / Ndim);
}

// ---------------- kernel 7: SE MLP (inv = scale applied to gmean/gsum) ---------
__global__ void __launch_bounds__(128) k_mlp(const float* __restrict__ gmean,
                                             const float* __restrict__ W,      // conv0_w [o][c]
                                             const float* __restrict__ conv_b,
                                             const float* __restrict__ fc1w,
                                             const float* __restrict__ fc1b,
                                             const float* __restrict__ fc2w,
                                             const float* __restrict__ fc2b,
                                             float inv,
                                             float* __restrict__ f2g) {
  __shared__ float gm[Cdim];
  __shared__ float sq[Cdim];
  __shared__ float f1[64];
  int b = blockIdx.x, tid = threadIdx.x;
  gm[tid] = gmean[b * Cdim + tid] * inv;
  __syncthreads();
  float a = conv_b[tid];
  const float* wr = W + tid * Cdim;
  for (int c = 0; c < Cdim; ++c) a = fmaf(wr[c], gm[c], a);
  sq[tid] = a;
  __syncthreads();
  if (tid < 64) {
    float a1 = fc1b[tid];
    for (int c = 0; c < Cdim; ++c) a1 = fmaf(fc1w[tid * Cdim + c], sq[c], a1);
    f1[tid] = 0.5f * a1 * (1.0f + erff(a1 * 0.7071067811865475244f));
  }
  __syncthreads();
  float a2 = fc2b[tid];
  for (int i = 0; i < 64; ++i) a2 = fmaf(fc2w[tid * 64 + i], f1[i], a2);
  f2g[b * Cdim + tid] = 1.0f / (1.0f + expf(-a2));
}

// ---------------- kernel 8a: pipelined multi-tile MFMA GEMM (unchanged R12) ----
__global__ void __launch_bounds__(1024) k_conv_g(
    const unsigned short* __restrict__ gpack,
    const unsigned short* __restrict__ Whs, const unsigned short* __restrict__ Wls,
    const float* __restrict__ bias, const float* __restrict__ f2g,
    float* __restrict__ out) {
  __shared__ unsigned short Whl[16384];   // 32KB
  __shared__ unsigned short Wll[16384];   // 32KB
  __shared__ unsigned short Bb[2][16384]; // 2x32KB
  __shared__ float bi_l[Cdim], f2_l[Cdim];
  int t = threadIdx.x;
  int blk = blockIdx.x;
  int b = blk >> 5;         // 32 blocks per b (4 tiles each = 128 tiles)
  int tile0 = blk * 4;
  if (t < 128) {
    bi_l[t] = bias[t];
    f2_l[t] = f2g[b * Cdim + t];
  }
  {
    const uint4* gw = (const uint4*)Whs;
    const uint4* gl = (const uint4*)Wls;
    const uint4* gb = (const uint4*)(gpack + (size_t)tile0 * 16384);
    uint4* lw = (uint4*)Whl;
    uint4* ll = (uint4*)Wll;
    uint4* lb = (uint4*)Bb[0];
    lw[t] = gw[t]; lw[t + 1024] = gw[t + 1024];
    ll[t] = gl[t]; ll[t + 1024] = gl[t + 1024];
    lb[t] = gb[t]; lb[t + 1024] = gb[t + 1024];
  }
  __syncthreads();
  int w = t >> 6, lane = t & 63;
  int wo = (w & 1) * 64, wn = (w >> 1) * 16;  // 2 o-halves x 8 n-groups
  int l15 = lane & 15, lg = lane >> 4;
  int nrow = wn + l15;
  int brow = nrow * 128;
  int bswz = nrow & 7;
  int cur = 0;
  for (int tt = 0; tt < 4; ++tt) {
    uint4 rb0, rb1;
    if (tt < 3) {
      const uint4* gb = (const uint4*)(gpack + (size_t)(tile0 + tt + 1) * 16384);
      rb0 = gb[t];
      rb1 = gb[t + 1024];
    }
    f32x4 acc[4];
#pragma unroll
    for (int of = 0; of < 4; ++of) acc[of] = (f32x4){0.f, 0.f, 0.f, 0.f};
#pragma unroll
    for (int kb = 0; kb < 4; ++kb) {
      int g = kb * 4 + lg;
      short8 bb = *(const short8*)&Bb[cur][brow + ((g ^ bswz) << 3)];
#pragma unroll
      for (int of = 0; of < 4; ++of) {
        int o = wo + of * 16 + l15;
        int apos = o * 128 + ((g ^ (o & 7)) << 3);
        short8 ah = *(const short8*)&Whl[apos];
        short8 al_ = *(const short8*)&Wll[apos];
        acc[of] = __builtin_amdgcn_mfma_f32_16x16x32_bf16(ah, bb, acc[of], 0, 0, 0);
        acc[of] = __builtin_amdgcn_mfma_f32_16x16x32_bf16(al_, bb, acc[of], 0, 0, 0);
      }
    }
    __syncthreads();
    if (tt < 3) {
      uint4* lb = (uint4*)Bb[cur ^ 1];
      lb[t] = rb0;
      lb[t + 1024] = rb1;
    }
    __syncthreads();
    int n0 = ((tile0 + tt) & 127) * 128;
#pragma unroll
    for (int of = 0; of < 4; ++of) {
#pragma unroll
      for (int r = 0; r < 4; ++r) {
        int o = wo + of * 16 + lg * 4 + r;
        out[((size_t)(b * Cdim + o)) * Ndim + n0 + wn + l15] =
            (acc[of][r] + bi_l[o]) * f2_l[o];
      }
    }
    cur ^= 1;
  }
}

// ---------------- kernel 8b (fallback): R7 fused conv (3-term, linear W) -------
__global__ void __launch_bounds__(512, 4) k_conv_x(
    const float* __restrict__ x, const signed char* __restrict__ kbin,
    const float* __restrict__ feat, const float* __restrict__ alpha,
    const float* __restrict__ beta,
    const unsigned short* __restrict__ Wh, const unsigned short* __restrict__ Wl,
    const float* __restrict__ bias, const float* __restrict__ f2g,
    float* __restrict__ out) {
  __shared__ unsigned g_hl[Cdim][132];
  __shared__ float feat_l[Cdim][Kdim];
  __shared__ float al_l[Cdim], be_l[Cdim], f2_l[Cdim], bi_l[Cdim];
  __shared__ signed char kb_l[128];
  int bx = blockIdx.x;
  int b = bx >> 7, nb = bx & 127;
  int n0 = nb * 128;
  int tid = threadIdx.x;
  for (int idx = tid; idx < Cdim * Kdim; idx += 512)
    ((float*)feat_l)[idx] = feat[b * Cdim * Kdim + idx];
  if (tid < Cdim) {
    al_l[tid] = alpha[b * Cdim + tid];
    be_l[tid] = beta[b * Cdim + tid];
    f2_l[tid] = f2g[b * Cdim + tid];
    bi_l[tid] = bias[tid];
  }
  if (tid >= 256 && tid < 384) kb_l[tid - 256] = kbin[b * Ndim + n0 + (tid - 256)];
  __syncthreads();
  for (int idx = tid; idx < Cdim * 32; idx += 512) {
    int c = idx >> 5, q4 = idx & 31;
    float4 xv = *(const float4*)(x + ((size_t)(b * Cdim + c)) * Ndim + n0 + q4 * 4);
    float a = al_l[c], be = be_l[c];
    float xe[4] = {xv.x, xv.y, xv.z, xv.w};
    unsigned r[4];
#pragma unroll
    for (int e = 0; e < 4; ++e) {
      int kb = kb_l[q4 * 4 + e];
      float rec = (kb >= 0) ? (xe[e] + feat_l[c][kb]) : 0.0f;
      float h = fmaf(a, rec, be);
      float g = 0.5f * h * (1.0f + erff(h * 0.7071067811865475244f));
      unsigned u = __float_as_uint(g);
      unsigned rh = (u + 0x7FFFu + ((u >> 16) & 1u)) & 0xFFFF0000u;
      float rr = g - __uint_as_float(rh);
      unsigned u2 = __float_as_uint(rr);
      unsigned rl = (u2 + 0x7FFFu + ((u2 >> 16) & 1u)) >> 16;
      r[e] = rh | rl;
    }
    int p4 = (q4 * 4) ^ (((c >> 3) & 1) << 4);
    *(uint4*)&g_hl[c][p4] = make_uint4(r[0], r[1], r[2], r[3]);
  }
  __syncthreads();
  int wid = tid >> 6, lane = tid & 63;
  int wo = (wid & 1) * 64;
  int wn = (wid >> 1) * 32;
  int l15 = lane & 15, lg = lane >> 4;
  f32x4 acc[4][2];
#pragma unroll
  for (int of = 0; of < 4; ++of)
#pragma unroll
    for (int nf = 0; nf < 2; ++nf) acc[of][nf] = (f32x4){0.f, 0.f, 0.f, 0.f};
#pragma unroll 2
  for (int kb = 0; kb < 4; ++kb) {
    int kbase = kb * 32 + lg * 8;
    short8 ah[4], alo[4];
#pragma unroll
    for (int of = 0; of < 4; ++of) {
      int o = wo + of * 16 + l15;
      ah[of] = *(const short8*)(Wh + o * Cdim + kbase);
      alo[of] = *(const short8*)(Wl + o * Cdim + kbase);
    }
#pragma unroll
    for (int nf = 0; nf < 2; ++nf) {
      int n = wn + nf * 16 + l15;
      int par = lg & 1;
      short8 bh, bl;
#pragma unroll
      for (int j = 0; j < 8; ++j) {
        unsigned u = g_hl[kbase + j][n ^ (par << 4)];
        bh[j] = (short)(u >> 16);
        bl[j] = (short)(u & 0xFFFFu);
      }
#pragma unroll
      for (int of = 0; of < 4; ++of) {
        acc[of][nf] = __builtin_amdgcn_mfma_f32_16x16x32_bf16(ah[of], bh, acc[of][nf], 0, 0, 0);
        acc[of][nf] = __builtin_amdgcn_mfma_f32_16x16x32_bf16(ah[of], bl, acc[of][nf], 0, 0, 0);
        acc[of][nf] = __builtin_amdgcn_mfma_f32_16x16x32_bf16(alo[of], bh, acc[of][nf], 0, 0, 0);
      }
    }
  }
#pragma unroll
  for (int of = 0; of < 4; ++of) {
#pragma unroll
    for (int nf = 0; nf < 2; ++nf) {
#pragma unroll
      for (int r = 0; r < 4; ++r) {
        int o = wo + of * 16 + lg * 4 + r;
        int n = wn + nf * 16 + l15;
        out[((size_t)(b * Cdim + o)) * Ndim + n0 + n] = (acc[of][nf][r] + bi_l[o]) * f2_l[o];
      }
    }
  }
}

extern "C" void kernel_launch(void* const* d_in, const int* in_sizes, int n_in,
                              void* d_out, int out_size, void* d_ws, size_t ws_size,
                              hipStream_t stream) {
  const float* x = (const float*)d_in[0];
  const float* logits = (const float*)d_in[1];
  const float* Wq1 = (const float*)d_in[2];
  const float* Wk1 = (const float*)d_in[3];
  const float* Wv1 = (const float*)d_in[4];
  const float* Wq2 = (const float*)d_in[5];
  const float* Wk2 = (const float*)d_in[6];
  const float* Wv2 = (const float*)d_in[7];
  const float* Wq3 = (const float*)d_in[8];
  const float* Wk3 = (const float*)d_in[9];
  const float* Wv3 = (const float*)d_in[10];
  const float* ln_w = (const float*)d_in[11];
  const float* ln_b = (const float*)d_in[12];
  const float* conv0_w = (const float*)d_in[13];
  const float* conv0_b = (const float*)d_in[14];
  const float* bn_w = (const float*)d_in[15];
  const float* bn_b = (const float*)d_in[16];
  const float* fc1_w = (const float*)d_in[17];
  const float* fc1_b = (const float*)d_in[18];
  const float* fc2_w = (const float*)d_in[19];
  const float* fc2_b = (const float*)d_in[20];
  float* out = (float*)d_out;

  char* p = (char*)d_ws;
  auto alloc = [&](size_t bytes) {
    char* r = p;
    p += (bytes + 255) & ~(size_t)255;
    return r;
  };
  signed char* kbin = (signed char*)alloc(Bdim * Ndim);
  int* cnt = (int*)alloc(Bdim * Kdim * 4);
  float* pooled = (float*)alloc(Bdim * Cdim * Kdim * 4);
  float* sxx = (float*)alloc(Bdim * Cdim * 4);
  float* feat = (float*)alloc(Bdim * Cdim * Kdim * 4);
  float* mu_i = (float*)alloc(Bdim * Cdim * 4);
  float* rs_i = (float*)alloc(Bdim * Cdim * 4);
  float* ratio = (float*)alloc(Bdim * Cdim * 4);
  float* alpha = (float*)alloc(Bdim * Cdim * 4);
  float* beta = (float*)alloc(Bdim * Cdim * 4);
  unsigned short* Wh = (unsigned short*)alloc(Cdim * Cdim * 2);
  unsigned short* Wlo = (unsigned short*)alloc(Cdim * Cdim * 2);
  unsigned short* Whs = (unsigned short*)alloc(Cdim * Cdim * 2);
  unsigned short* Wls = (unsigned short*)alloc(Cdim * Cdim * 2);
  unsigned short* Wbf = (unsigned short*)alloc(9 * Cdim * Cdim * 2);  // 288KB bf16
  float* f2g = (float*)alloc(Bdim * Cdim * 4);
  float* gmean = (float*)alloc(Bdim * Cdim * 4);
  float* warmdummy = (float*)alloc(576 * 4 * 4);
  unsigned short* gpack = (unsigned short*)alloc((size_t)Bdim * Cdim * Ndim * 2);  // 32 MiB
  bool fast = ((size_t)(p - (char*)d_ws) <= ws_size);

  k_prep<<<640, 256, 0, stream>>>(conv0_w, Wh, Wlo, Whs, Wls,
                                  Wq1, Wk1, Wv1, Wq2, Wk2, Wv2, Wq3, Wk3, Wv3,
                                  Wbf, cnt, gmean);
  k_bin<<<Bdim * Ndim / 256, 256, 0, stream>>>(logits, kbin, cnt);
  k_pool<<<Bdim * Cdim, 256, 0, stream>>>(x, kbin, pooled, sxx);
  // warm bf16 W into every XCD's L2 AFTER k_pool's 67MB stream evicted it
  k_warm<<<576, 256, 0, stream>>>(Wbf, warmdummy);
  k_xform<<<Bdim, 1024, 0, stream>>>(pooled, cnt, sxx, Wbf, ln_w, ln_b,
                                     feat, mu_i, rs_i, ratio);
  if (fast) {
    k_gpack<<<Bdim * 128, 256, 0, stream>>>(x, kbin, feat, mu_i, rs_i, ratio, bn_w, bn_b,
                                            gpack, gmean);
    k_mlp<<<Bdim, 128, 0, stream>>>(gmean, conv0_w, conv0_b, fc1_w, fc1_b, fc2_w, fc2_b,
                                    1.0f / Ndim, f2g);
    k_conv_g<<<256, 1024, 0, stream>>>(gpack, Whs, Wls, conv0_b, f2g, out);
  } else {
    k_alpha<<<1, 128, 0, stream>>>(mu_i, rs_i, ratio, bn_w, bn_b, alpha, beta);
    k_gmean<<<Bdim * Cdim, 256, 0, stream>>>(x, kbin, feat, alpha, beta, gmean);
    k_mlp<<<Bdim, 128, 0, stream>>>(gmean, conv0_w, conv0_b, fc1_w, fc1_b, fc2_w, fc2_b,
                                    1.0f, f2g);
    k_conv_x<<<Bdim * (Ndim / 128), 512, 0, stream>>>(x, kbin, feat, alpha, beta, Wh, Wlo,
                                                      conv0_b, f2g, out);
  }
}

// Round 19
// 115.600 us; speedup vs baseline: 1.1602x; 1.0448x over previous
//
#include <hip/hip_runtime.h>
#include <math.h>

#define Bdim 8
#define Cdim 128
#define Ndim 16384
#define Kdim 8

typedef __attribute__((ext_vector_type(8))) short short8;
typedef __attribute__((ext_vector_type(4))) float f32x4;

__device__ __forceinline__ unsigned rne16(float x) {
  unsigned u = __float_as_uint(x);
  return (u + 0x7FFFu + ((u >> 16) & 1u)) >> 16;
}

// fast exact-GELU: A&S 7.1.26 erf (abs err 1.5e-7 << bf16 lsb), hw rcp+exp,
// branch-free. Validated numerically in R15 (absmax unchanged at 0.0156).
__device__ __forceinline__ float fast_gelu(float h) {
  float z = fabsf(h) * 0.70710678118654752440f;
  float t = __builtin_amdgcn_rcpf(fmaf(0.3275911f, z, 1.0f));
  float p = t * fmaf(t, fmaf(t, fmaf(t, fmaf(t, 1.061405429f, -1.453152027f),
                                     1.421413741f), -0.284496736f), 0.254829592f);
  float er = fmaf(-p, __expf(-z * z), 1.0f);   // erf(|z|)
  float phi = 0.5f + copysignf(0.5f * er, h);
  return h * phi;
}

// ---------------- kernel 0: merged prep (wsplit + wprep + zero cnt/gmean) ------
__global__ void __launch_bounds__(256) k_prep(
    const float* __restrict__ W, unsigned short* __restrict__ Wh,
    unsigned short* __restrict__ Wl, unsigned short* __restrict__ Whs,
    unsigned short* __restrict__ Wls,
    const float* __restrict__ p0, const float* __restrict__ p1, const float* __restrict__ p2,
    const float* __restrict__ p3, const float* __restrict__ p4, const float* __restrict__ p5,
    const float* __restrict__ p6, const float* __restrict__ p7, const float* __restrict__ p8,
    unsigned short* __restrict__ Wbf, int* __restrict__ cnt, float* __restrict__ gmean) {
  int blk = blockIdx.x, t = threadIdx.x;
  if (blk < 64) {
    int idx = blk * 256 + t;  // 16384, [o][c] row-major
    int o = idx >> 7, c = idx & 127;
    float v = W[idx];
    unsigned u = __float_as_uint(v);
    unsigned rh = (u + 0x7FFFu + ((u >> 16) & 1u)) & 0xFFFF0000u;
    float vh = __uint_as_float(rh);
    float r = v - vh;  // exact
    unsigned u2 = __float_as_uint(r);
    unsigned rl = (u2 + 0x7FFFu + ((u2 >> 16) & 1u)) >> 16;
    unsigned short hs = (unsigned short)(rh >> 16);
    unsigned short ls = (unsigned short)rl;
    Wh[idx] = hs;
    Wl[idx] = ls;
    int pos = o * 128 + (((c >> 3) ^ (o & 7)) << 3) + (c & 7);
    Whs[pos] = hs;
    Wls[pos] = ls;
    if (blk == 0 && t < Bdim * Kdim) cnt[t] = 0;
    if (blk < 4) gmean[blk * 256 + t] = 0.f;
  } else {
    int m = (blk - 64) >> 6;                 // 9 matrices x 64 blocks
    int i = ((blk - 64) & 63) * 256 + t;
    const float* mp = m == 0 ? p0 : m == 1 ? p1 : m == 2 ? p2 : m == 3 ? p3 : m == 4 ? p4
                    : m == 5 ? p5 : m == 6 ? p6 : m == 7 ? p7 : p8;
    Wbf[m * 16384 + i] = (unsigned short)rne16(mp[i]);
  }
}

// ---------------- kernel 1: bin assignment + counts ----------------
__global__ void __launch_bounds__(256) k_bin(const float* __restrict__ logits,
                                             signed char* __restrict__ kbin,
                                             int* __restrict__ cnt) {
  __shared__ int h[Kdim];
  int tid = threadIdx.x;
  if (tid < Kdim) h[tid] = 0;
  __syncthreads();
  int idx = blockIdx.x * 256 + tid;              // < B*N, block stays in one b
  int b = idx >> 14;                             // /16384
  float w = tanhf(logits[idx]);
  int kb = -1;
#pragma unroll
  for (int j = 0; j < Kdim; ++j) {
    float lo = -1.0f + 0.25f * (float)j;
    float hi = lo + 0.25f;
    if (w > lo && w <= hi && w != 0.0f) kb = j;
  }
  kbin[idx] = (signed char)kb;
  if (kb >= 0) atomicAdd(&h[kb], 1);
  __syncthreads();
  if (tid < Kdim) atomicAdd(&cnt[b * Kdim + tid], h[tid]);
}

// ---------------- kernel 2: per-(b,c) masked pooling + masked sum of squares ----
__global__ void __launch_bounds__(256) k_pool(const float* __restrict__ x,
                                              const signed char* __restrict__ kbin,
                                              float* __restrict__ pooled,
                                              float* __restrict__ sxx) {
  int bc = blockIdx.x;                 // b*C + c
  int b = bc >> 7;
  const float4* xr = (const float4*)(x + (size_t)bc * Ndim);
  const char4* kr = (const char4*)(kbin + b * Ndim);
  float acc[Kdim];
#pragma unroll
  for (int j = 0; j < Kdim; ++j) acc[j] = 0.f;
  float s2 = 0.f;
  int tid = threadIdx.x;
  for (int n4 = tid; n4 < Ndim / 4; n4 += 256) {
    float4 v = xr[n4];
    char4 kb = kr[n4];
    float ve[4] = {v.x, v.y, v.z, v.w};
    signed char ke[4] = {kb.x, kb.y, kb.z, kb.w};
#pragma unroll
    for (int e = 0; e < 4; ++e) {
      float xv = ve[e];
      int kv = ke[e];
      if (kv >= 0) s2 += xv * xv;
#pragma unroll
      for (int j = 0; j < Kdim; ++j) acc[j] += (kv == j) ? xv : 0.f;
    }
  }
#pragma unroll
  for (int off = 32; off > 0; off >>= 1) {
#pragma unroll
    for (int j = 0; j < Kdim; ++j) acc[j] += __shfl_down(acc[j], off);
    s2 += __shfl_down(s2, off);
  }
  __shared__ float red[4][Kdim + 1];
  int wv = tid >> 6, ln = tid & 63;
  if (ln == 0) {
#pragma unroll
    for (int j = 0; j < Kdim; ++j) red[wv][j] = acc[j];
    red[wv][Kdim] = s2;
  }
  __syncthreads();
  if (tid < Kdim) pooled[bc * Kdim + tid] = red[0][tid] + red[1][tid] + red[2][tid] + red[3][tid];
  if (tid == Kdim) sxx[bc] = red[0][Kdim] + red[1][Kdim] + red[2][Kdim] + red[3][Kdim];
}

// ---------------- kernel 2.5: warm bf16 W into every XCD's L2 ------------------
__global__ void __launch_bounds__(256) k_warm(const unsigned short* __restrict__ Wbf,
                                              float* __restrict__ dummy) {
  int g = blockIdx.x >> 3;   // 72 slices x 8 XCD copies
  int t = threadIdx.x;
  int idx = g * 256 + t;     // uint4 index into 9*16384 ushorts = 18432 uint4
  uint4 v = ((const uint4*)Wbf)[idx];
  float s = (float)(v.x ^ v.y ^ v.z ^ v.w);
#pragma unroll
  for (int off = 32; off > 0; off >>= 1) s += __shfl_down(s, off);
  if ((t & 63) == 0) dummy[blockIdx.x * 4 + (t >> 6)] = s;  // keep loads live
}

// ---------------- kernel 3: 3-layer transformer v8 (MFMA projections) ----------
__global__ void __launch_bounds__(1024) k_xform(
    const float* __restrict__ pooled, const int* __restrict__ cnt,
    const float* __restrict__ sxx, const unsigned short* __restrict__ Wbf,
    const float* __restrict__ ln_w, const float* __restrict__ ln_b,
    float* __restrict__ feat, float* __restrict__ mu_i, float* __restrict__ rs_i,
    float* __restrict__ ratio) {
  __shared__ float f_l[Kdim][132], q_l[Kdim][132], kk_l[Kdim][132], v_l[Kdim][132];
  __shared__ unsigned short fTh[16][132], fTl[16][132];  // B operand rows j (8 used)
  __shared__ float part[Kdim][Kdim][Cdim];
  __shared__ float pm[Kdim][Cdim], ps[Kdim][Cdim];
  __shared__ float lnw_l[Cdim], lnb_l[Cdim];
  __shared__ float cnt_raw[Kdim], cnt_div[Kdim];
  __shared__ float redA[Kdim][2], redB[Kdim][2];
  int b = blockIdx.x, tid = threadIdx.x;
  int c_ = tid & 127, h_ = tid >> 7;
  int o8 = tid >> 3, j8 = tid & 7;
  int wid = tid >> 6, lane = tid & 63;
  int l15 = lane & 15, lg = lane >> 4;
  const float inv_temp = 0.08838834764831845f;

  if (tid < Kdim) {
    int cc = cnt[b * Kdim + tid];
    cnt_raw[tid] = (float)cc;
    cnt_div[tid] = (float)(cc == 0 ? 1 : cc);
  }
  if (tid >= 128 && tid < 256) lnw_l[tid - 128] = ln_w[tid - 128];
  if (tid >= 256 && tid < 384) lnb_l[tid - 256] = ln_b[tid - 256];
  __syncthreads();
  {
    float fv = pooled[(b * Cdim + o8) * Kdim + j8] / cnt_div[j8];
    f_l[j8][o8] = fv;
    unsigned hi = rne16(fv);
    fTh[j8][o8] = (unsigned short)hi;
    fTl[j8][o8] = (unsigned short)rne16(fv - __uint_as_float(hi << 16));
  }
  float t_carry = 0.f;
  float sv[16];
  float mloc = 0.f;
  for (int layer = 0; layer < 3; ++layer) {
    // ---- s1: LN-finish (layer>0) writes f_l + fT ----
    if (layer > 0) {
      float S1 = redA[h_][0] + redA[h_][1];
      float S2 = redB[h_][0] + redB[h_][1];
      float mu = S1 * (1.f / Cdim);
      float var = S2 * (1.f / Cdim) - mu * mu;
      float rs = rsqrtf(var + 1e-6f);
      float fv = (t_carry - mu) * rs * lnw_l[c_] + lnb_l[c_];
      f_l[h_][c_] = fv;
      unsigned hi = rne16(fv);
      fTh[h_][c_] = (unsigned short)hi;
      fTl[h_][c_] = (unsigned short)rne16(fv - __uint_as_float(hi << 16));
    }
    __syncthreads();
    // ---- s2: MFMA projections (24 jobs over 16 waves) ----
    for (int job = wid; job < 24; job += 16) {
      int m = job >> 3, ot = job & 7;
      const unsigned short* A = Wbf + (size_t)(layer * 3 + m) * 16384 + (ot * 16 + l15) * 128;
      f32x4 acc = (f32x4){0.f, 0.f, 0.f, 0.f};
#pragma unroll
      for (int ks = 0; ks < 4; ++ks) {
        int kbase = ks * 32 + lg * 8;
        short8 a = *(const short8*)(A + kbase);
        short8 bh = *(const short8*)&fTh[l15][kbase];
        short8 bl = *(const short8*)&fTl[l15][kbase];
        acc = __builtin_amdgcn_mfma_f32_16x16x32_bf16(a, bh, acc, 0, 0, 0);
        acc = __builtin_amdgcn_mfma_f32_16x16x32_bf16(a, bl, acc, 0, 0, 0);
      }
      if (l15 < 8) {
#pragma unroll
        for (int r = 0; r < 4; ++r) {
          int o = ot * 16 + lg * 4 + r;
          float v = acc[r];
          if (m == 0) q_l[l15][o] = v * inv_temp;
          else if (m == 1) kk_l[l15][o] = v;
          else v_l[l15][o] = v;
        }
      }
    }
    __syncthreads();
    // ---- s3: local scores + local max/expsum (online softmax) ----
    {
      int d0 = h_ * 16;
      float qv[8];
#pragma unroll
      for (int j = 0; j < 8; ++j) qv[j] = q_l[j][c_];  // lane-consecutive
#pragma unroll
      for (int dd = 0; dd < 16; ++dd) sv[dd] = 0.f;
#pragma unroll
      for (int j = 0; j < 8; ++j) {
#pragma unroll
        for (int d4 = 0; d4 < 4; ++d4) {
          float4 k4 = *(const float4*)&kk_l[j][d0 + d4 * 4];  // broadcast
          sv[d4 * 4 + 0] = fmaf(qv[j], k4.x, sv[d4 * 4 + 0]);
          sv[d4 * 4 + 1] = fmaf(qv[j], k4.y, sv[d4 * 4 + 1]);
          sv[d4 * 4 + 2] = fmaf(qv[j], k4.z, sv[d4 * 4 + 2]);
          sv[d4 * 4 + 3] = fmaf(qv[j], k4.w, sv[d4 * 4 + 3]);
        }
      }
      mloc = sv[0];
#pragma unroll
      for (int dd = 1; dd < 16; ++dd) mloc = fmaxf(mloc, sv[dd]);
      float sl = 0.f;
#pragma unroll
      for (int dd = 0; dd < 16; ++dd) {
        sv[dd] = expf(sv[dd] - mloc);
        sl += sv[dd];
      }
      pm[h_][c_] = mloc;
      ps[h_][c_] = sl;
    }
    __syncthreads();
    // ---- s4: global softmax rescale + PV partials ----
    {
      float M = pm[0][c_];
#pragma unroll
      for (int hh = 1; hh < 8; ++hh) M = fmaxf(M, pm[hh][c_]);
      float S = 0.f;
#pragma unroll
      for (int hh = 0; hh < 8; ++hh) S += ps[hh][c_] * expf(pm[hh][c_] - M);
      float fac = expf(mloc - M) / S;
#pragma unroll
      for (int dd = 0; dd < 16; ++dd) sv[dd] *= fac;
      int d0 = h_ * 16;
#pragma unroll
      for (int j = 0; j < 8; ++j) {
        float po = 0.f;
#pragma unroll
        for (int d4 = 0; d4 < 4; ++d4) {
          float4 v4 = *(const float4*)&v_l[j][d0 + d4 * 4];  // broadcast
          po = fmaf(sv[d4 * 4 + 0], v4.x, po);
          po = fmaf(sv[d4 * 4 + 1], v4.y, po);
          po = fmaf(sv[d4 * 4 + 2], v4.z, po);
          po = fmaf(sv[d4 * 4 + 3], v4.w, po);
        }
        part[h_][j][c_] = po;  // lane-consecutive
      }
    }
    __syncthreads();
    // ---- s5: combine partials + residual + LN reduce ----
    {
      float t = f_l[h_][c_];
#pragma unroll
      for (int hh = 0; hh < 8; ++hh) t += part[hh][h_][c_];
      t_carry = t;
      float s1 = t, s2 = t * t;
#pragma unroll
      for (int off = 32; off > 0; off >>= 1) {
        s1 += __shfl_xor(s1, off);
        s2 += __shfl_xor(s2, off);
      }
      int wv = (tid >> 6) & 1;
      if ((tid & 63) == 0) { redA[h_][wv] = s1; redB[h_][wv] = s2; }
    }
    __syncthreads();
  }
  // ---- epilogue LN-finish ----
  {
    float S1 = redA[h_][0] + redA[h_][1];
    float S2 = redB[h_][0] + redB[h_][1];
    float mu = S1 * (1.f / Cdim);
    float var = S2 * (1.f / Cdim) - mu * mu;
    float rs = rsqrtf(var + 1e-6f);
    f_l[h_][c_] = (t_carry - mu) * rs * lnw_l[c_] + lnb_l[c_];
  }
  __syncthreads();
  // ---- closed-form instance-norm stats ----
  if (tid < Cdim) {
    int c = tid;
    float S1 = 0.f, S2c = 0.f;
#pragma unroll
    for (int j = 0; j < Kdim; ++j) {
      float pl = pooled[(b * Cdim + c) * Kdim + j];
      float fe = f_l[j][c];
      feat[(b * Cdim + c) * Kdim + j] = fe;
      S1 += pl + cnt_raw[j] * fe;
      S2c += 2.f * pl * fe + cnt_raw[j] * fe * fe;
    }
    float S2 = sxx[b * Cdim + c] + S2c;
    float mu = S1 * (1.f / Ndim);
    float var = S2 * (1.f / Ndim) - mu * mu;
    float rs = rsqrtf(var + 1e-5f);
    mu_i[b * Cdim + c] = mu;
    rs_i[b * Cdim + c] = rs;
    ratio[b * Cdim + c] = var * rs * rs;
  }
}

// ---------------- kernel 4: fold norms into affine (fallback path only) --------
__global__ void k_alpha(const float* __restrict__ mu_i, const float* __restrict__ rs_i,
                        const float* __restrict__ ratio, const float* __restrict__ bn_w,
                        const float* __restrict__ bn_b, float* __restrict__ alpha,
                        float* __restrict__ beta) {
  int c = threadIdx.x;
  float vb = 0.f;
  for (int b = 0; b < Bdim; ++b) vb += ratio[b * Cdim + c];
  vb *= (1.f / Bdim);
  float rsb = rsqrtf(vb + 1e-5f);
  float w = bn_w[c], bb = bn_b[c];
  for (int b = 0; b < Bdim; ++b) {
    float a = rs_i[b * Cdim + c] * rsb * w;
    alpha[b * Cdim + c] = a;
    beta[b * Cdim + c] = bb - mu_i[b * Cdim + c] * a;
  }
}

// ---------------- kernel 6a: gelu once -> transposed swizzled bf16 tiles -------
// (R16 structure; ONLY change this round: erff -> branch-free fast_gelu)
__global__ void __launch_bounds__(256) k_gpack(
    const float* __restrict__ x, const signed char* __restrict__ kbin,
    const float* __restrict__ feat,
    const float* __restrict__ mu_i, const float* __restrict__ rs_i,
    const float* __restrict__ ratio, const float* __restrict__ bn_w,
    const float* __restrict__ bn_b, unsigned short* __restrict__ gpack,
    float* __restrict__ gsum) {
  __shared__ unsigned short xg[Cdim][132];   // [c][n] bf16 (33.8KB)
  __shared__ float feat_l[Cdim][Kdim];
  __shared__ float al_l[Cdim], be_l[Cdim];
  __shared__ signed char kb_l[128];
  int tile = blockIdx.x;
  int b = tile >> 7, nb = tile & 127;
  int n0 = nb * 128;
  int t = threadIdx.x;
  for (int idx = t; idx < Cdim * Kdim; idx += 256)
    ((float*)feat_l)[idx] = feat[b * Cdim * Kdim + idx];
  if (t < 128) {
    int c = t;
    float vb = 0.f;
#pragma unroll
    for (int bb = 0; bb < Bdim; ++bb) vb += ratio[bb * Cdim + c];
    vb *= (1.f / Bdim);
    float rsb = rsqrtf(vb + 1e-5f);
    float a = rs_i[b * Cdim + c] * rsb * bn_w[c];
    al_l[c] = a;
    be_l[c] = bn_b[c] - mu_i[b * Cdim + c] * a;
    kb_l[c] = kbin[b * Ndim + n0 + c];
  }
  __syncthreads();
#pragma unroll 4
  for (int it = 0; it < 16; ++it) {
    int idx = it * 256 + t;
    int q = idx & 31, c = idx >> 5;
    float4 xv = *(const float4*)(x + ((size_t)(b * Cdim + c)) * Ndim + n0 + q * 4);
    float a = al_l[c], be = be_l[c];
    float xe[4] = {xv.x, xv.y, xv.z, xv.w};
    unsigned short rr[4];
#pragma unroll
    for (int e = 0; e < 4; ++e) {
      int kb = kb_l[q * 4 + e];
      float rec = (kb >= 0) ? (xe[e] + feat_l[c][kb]) : 0.0f;
      float h = fmaf(a, rec, be);
      float g = fast_gelu(h);
      rr[e] = (unsigned short)rne16(g);
    }
    *(ushort4*)&xg[c][q * 4] = make_ushort4(rr[0], rr[1], rr[2], rr[3]);
  }
  __syncthreads();
  {
    int c = t >> 1, half = t & 1;
    float s = 0.f;
#pragma unroll 8
    for (int i = 0; i < 64; ++i) {
      unsigned us = xg[c][half * 64 + i];
      s += __uint_as_float(us << 16);
    }
    s += __shfl_xor(s, 1);
    if (half == 0) atomicAdd(&gsum[b * Cdim + c], s);
  }
  unsigned short* tb = gpack + (size_t)tile * 16384;
#pragma unroll 2
  for (int it = 0; it < 8; ++it) {
    int idx = it * 256 + t;
    int cg = idx & 15, n = idx >> 4;
    unsigned u32s[4];
#pragma unroll
    for (int p = 0; p < 4; ++p) {
      unsigned lo = xg[cg * 8 + 2 * p][n];
      unsigned hi = xg[cg * 8 + 2 * p + 1][n];
      u32s[p] = lo | (hi << 16);
    }
    int g = cg ^ (n & 7);
    *(uint4*)(tb + n * 128 + g * 8) = make_uint4(u32s[0], u32s[1], u32s[2], u32s[3]);
  }
}

// ---------------- kernel 6b (fallback): per-(b,c) mean of GELU'd activations ---
__global__ void __launch_bounds__(256) k_gmean(
    const float* __restrict__ x, const signed char* __restrict__ kbin,
    const float* __restrict__ feat, const float* __restrict__ alpha,
    const float* __restrict__ beta, float* __restrict__ gmean) {
  int bc = blockIdx.x;
  int b = bc >> 7;
  __shared__ float fl[Kdim];
  int tid = threadIdx.x;
  if (tid < Kdim) fl[tid] = feat[bc * Kdim + tid];
  __syncthreads();
  float a = alpha[bc], be = beta[bc];
  const float4* xr = (const float4*)(x + (size_t)bc * Ndim);
  const char4* kr = (const char4*)(kbin + b * Ndim);
  float s = 0.f;
  for (int n4 = tid; n4 < Ndim / 4; n4 += 256) {
    float4 v = xr[n4];
    char4 kb = kr[n4];
    float ve[4] = {v.x, v.y, v.z, v.w};
    signed char ke[4] = {kb.x, kb.y, kb.z, kb.w};
#pragma unroll
    for (int e = 0; e < 4; ++e) {
      int kv = ke[e];
      float rec = 0.f;
#pragma unroll
      for (int j = 0; j < Kdim; ++j) rec += (kv == j) ? (ve[e] + fl[j]) : 0.f;
      float h = fmaf(a, rec, be);
      s += 0.5f * h * (1.0f + erff(h * 0.7071067811865475244f));
    }
  }
#pragma unroll
  for (int off = 32; off > 0; off >>= 1) s += __shfl_down(s, off);
  __shared__ float red[4];
  int wv = tid >> 6;
  if ((tid & 63) == 0) red[wv] = s;
  __syncthreads();
  if (tid == 0) gmean[bc] = (red[0] + red[1] + red[2] + red[3]) * (1.0f / Ndim);
}

// ---------------- kernel 7: SE MLP (inv = scale applied to gmean/gsum) ---------
__global__ void __launch_bounds__(128) k_mlp(const float* __restrict__ gmean,
                                             const float* __restrict__ W,      // conv0_w [o][c]
                                             const float* __restrict__ conv_b,
                                             const float* __restrict__ fc1w,
                                             const float* __restrict__ fc1b,
                                             const float* __restrict__ fc2w,
                                             const float* __restrict__ fc2b,
                                             float inv,
                                             float* __restrict__ f2g) {
  __shared__ float gm[Cdim];
  __shared__ float sq[Cdim];
  __shared__ float f1[64];
  int b = blockIdx.x, tid = threadIdx.x;
  gm[tid] = gmean[b * Cdim + tid] * inv;
  __syncthreads();
  float a = conv_b[tid];
  const float* wr = W + tid * Cdim;
  for (int c = 0; c < Cdim; ++c) a = fmaf(wr[c], gm[c], a);
  sq[tid] = a;
  __syncthreads();
  if (tid < 64) {
    float a1 = fc1b[tid];
    for (int c = 0; c < Cdim; ++c) a1 = fmaf(fc1w[tid * Cdim + c], sq[c], a1);
    f1[tid] = 0.5f * a1 * (1.0f + erff(a1 * 0.7071067811865475244f));
  }
  __syncthreads();
  float a2 = fc2b[tid];
  for (int i = 0; i < 64; ++i) a2 = fmaf(fc2w[tid * 64 + i], f1[i], a2);
  f2g[b * Cdim + tid] = 1.0f / (1.0f + expf(-a2));
}

// ---------------- kernel 8a: pipelined multi-tile MFMA GEMM (unchanged R12) ----
__global__ void __launch_bounds__(1024) k_conv_g(
    const unsigned short* __restrict__ gpack,
    const unsigned short* __restrict__ Whs, const unsigned short* __restrict__ Wls,
    const float* __restrict__ bias, const float* __restrict__ f2g,
    float* __restrict__ out) {
  __shared__ unsigned short Whl[16384];   // 32KB
  __shared__ unsigned short Wll[16384];   // 32KB
  __shared__ unsigned short Bb[2][16384]; // 2x32KB
  __shared__ float bi_l[Cdim], f2_l[Cdim];
  int t = threadIdx.x;
  int blk = blockIdx.x;
  int b = blk >> 5;         // 32 blocks per b (4 tiles each = 128 tiles)
  int tile0 = blk * 4;
  if (t < 128) {
    bi_l[t] = bias[t];
    f2_l[t] = f2g[b * Cdim + t];
  }
  {
    const uint4* gw = (const uint4*)Whs;
    const uint4* gl = (const uint4*)Wls;
    const uint4* gb = (const uint4*)(gpack + (size_t)tile0 * 16384);
    uint4* lw = (uint4*)Whl;
    uint4* ll = (uint4*)Wll;
    uint4* lb = (uint4*)Bb[0];
    lw[t] = gw[t]; lw[t + 1024] = gw[t + 1024];
    ll[t] = gl[t]; ll[t + 1024] = gl[t + 1024];
    lb[t] = gb[t]; lb[t + 1024] = gb[t + 1024];
  }
  __syncthreads();
  int w = t >> 6, lane = t & 63;
  int wo = (w & 1) * 64, wn = (w >> 1) * 16;  // 2 o-halves x 8 n-groups
  int l15 = lane & 15, lg = lane >> 4;
  int nrow = wn + l15;
  int brow = nrow * 128;
  int bswz = nrow & 7;
  int cur = 0;
  for (int tt = 0; tt < 4; ++tt) {
    uint4 rb0, rb1;
    if (tt < 3) {
      const uint4* gb = (const uint4*)(gpack + (size_t)(tile0 + tt + 1) * 16384);
      rb0 = gb[t];
      rb1 = gb[t + 1024];
    }
    f32x4 acc[4];
#pragma unroll
    for (int of = 0; of < 4; ++of) acc[of] = (f32x4){0.f, 0.f, 0.f, 0.f};
#pragma unroll
    for (int kb = 0; kb < 4; ++kb) {
      int g = kb * 4 + lg;
      short8 bb = *(const short8*)&Bb[cur][brow + ((g ^ bswz) << 3)];
#pragma unroll
      for (int of = 0; of < 4; ++of) {
        int o = wo + of * 16 + l15;
        int apos = o * 128 + ((g ^ (o & 7)) << 3);
        short8 ah = *(const short8*)&Whl[apos];
        short8 al_ = *(const short8*)&Wll[apos];
        acc[of] = __builtin_amdgcn_mfma_f32_16x16x32_bf16(ah, bb, acc[of], 0, 0, 0);
        acc[of] = __builtin_amdgcn_mfma_f32_16x16x32_bf16(al_, bb, acc[of], 0, 0, 0);
      }
    }
    __syncthreads();
    if (tt < 3) {
      uint4* lb = (uint4*)Bb[cur ^ 1];
      lb[t] = rb0;
      lb[t + 1024] = rb1;
    }
    __syncthreads();
    int n0 = ((tile0 + tt) & 127) * 128;
#pragma unroll
    for (int of = 0; of < 4; ++of) {
#pragma unroll
      for (int r = 0; r < 4; ++r) {
        int o = wo + of * 16 + lg * 4 + r;
        out[((size_t)(b * Cdim + o)) * Ndim + n0 + wn + l15] =
            (acc[of][r] + bi_l[o]) * f2_l[o];
      }
    }
    cur ^= 1;
  }
}

// ---------------- kernel 8b (fallback): R7 fused conv (3-term, linear W) -------
__global__ void __launch_bounds__(512, 4) k_conv_x(
    const float* __restrict__ x, const signed char* __restrict__ kbin,
    const float* __restrict__ feat, const float* __restrict__ alpha,
    const float* __restrict__ beta,
    const unsigned short* __restrict__ Wh, const unsigned short* __restrict__ Wl,
    const float* __restrict__ bias, const float* __restrict__ f2g,
    float* __restrict__ out) {
  __shared__ unsigned g_hl[Cdim][132];
  __shared__ float feat_l[Cdim][Kdim];
  __shared__ float al_l[Cdim], be_l[Cdim], f2_l[Cdim], bi_l[Cdim];
  __shared__ signed char kb_l[128];
  int bx = blockIdx.x;
  int b = bx >> 7, nb = bx & 127;
  int n0 = nb * 128;
  int tid = threadIdx.x;
  for (int idx = tid; idx < Cdim * Kdim; idx += 512)
    ((float*)feat_l)[idx] = feat[b * Cdim * Kdim + idx];
  if (tid < Cdim) {
    al_l[tid] = alpha[b * Cdim + tid];
    be_l[tid] = beta[b * Cdim + tid];
    f2_l[tid] = f2g[b * Cdim + tid];
    bi_l[tid] = bias[tid];
  }
  if (tid >= 256 && tid < 384) kb_l[tid - 256] = kbin[b * Ndim + n0 + (tid - 256)];
  __syncthreads();
  for (int idx = tid; idx < Cdim * 32; idx += 512) {
    int c = idx >> 5, q4 = idx & 31;
    float4 xv = *(const float4*)(x + ((size_t)(b * Cdim + c)) * Ndim + n0 + q4 * 4);
    float a = al_l[c], be = be_l[c];
    float xe[4] = {xv.x, xv.y, xv.z, xv.w};
    unsigned r[4];
#pragma unroll
    for (int e = 0; e < 4; ++e) {
      int kb = kb_l[q4 * 4 + e];
      float rec = (kb >= 0) ? (xe[e] + feat_l[c][kb]) : 0.0f;
      float h = fmaf(a, rec, be);
      float g = 0.5f * h * (1.0f + erff(h * 0.7071067811865475244f));
      unsigned u = __float_as_uint(g);
      unsigned rh = (u + 0x7FFFu + ((u >> 16) & 1u)) & 0xFFFF0000u;
      float rr = g - __uint_as_float(rh);
      unsigned u2 = __float_as_uint(rr);
      unsigned rl = (u2 + 0x7FFFu + ((u2 >> 16) & 1u)) >> 16;
      r[e] = rh | rl;
    }
    int p4 = (q4 * 4) ^ (((c >> 3) & 1) << 4);
    *(uint4*)&g_hl[c][p4] = make_uint4(r[0], r[1], r[2], r[3]);
  }
  __syncthreads();
  int wid = tid >> 6, lane = tid & 63;
  int wo = (wid & 1) * 64;
  int wn = (wid >> 1) * 32;
  int l15 = lane & 15, lg = lane >> 4;
  f32x4 acc[4][2];
#pragma unroll
  for (int of = 0; of < 4; ++of)
#pragma unroll
    for (int nf = 0; nf < 2; ++nf) acc[of][nf] = (f32x4){0.f, 0.f, 0.f, 0.f};
#pragma unroll 2
  for (int kb = 0; kb < 4; ++kb) {
    int kbase = kb * 32 + lg * 8;
    short8 ah[4], alo[4];
#pragma unroll
    for (int of = 0; of < 4; ++of) {
      int o = wo + of * 16 + l15;
      ah[of] = *(const short8*)(Wh + o * Cdim + kbase);
      alo[of] = *(const short8*)(Wl + o * Cdim + kbase);
    }
#pragma unroll
    for (int nf = 0; nf < 2; ++nf) {
      int n = wn + nf * 16 + l15;
      int par = lg & 1;
      short8 bh, bl;
#pragma unroll
      for (int j = 0; j < 8; ++j) {
        unsigned u = g_hl[kbase + j][n ^ (par << 4)];
        bh[j] = (short)(u >> 16);
        bl[j] = (short)(u & 0xFFFFu);
      }
#pragma unroll
      for (int of = 0; of < 4; ++of) {
        acc[of][nf] = __builtin_amdgcn_mfma_f32_16x16x32_bf16(ah[of], bh, acc[of][nf], 0, 0, 0);
        acc[of][nf] = __builtin_amdgcn_mfma_f32_16x16x32_bf16(ah[of], bl, acc[of][nf], 0, 0, 0);
        acc[of][nf] = __builtin_amdgcn_mfma_f32_16x16x32_bf16(alo[of], bh, acc[of][nf], 0, 0, 0);
      }
    }
  }
#pragma unroll
  for (int of = 0; of < 4; ++of) {
#pragma unroll
    for (int nf = 0; nf < 2; ++nf) {
#pragma unroll
      for (int r = 0; r < 4; ++r) {
        int o = wo + of * 16 + lg * 4 + r;
        int n = wn + nf * 16 + l15;
        out[((size_t)(b * Cdim + o)) * Ndim + n0 + n] = (acc[of][nf][r] + bi_l[o]) * f2_l[o];
      }
    }
  }
}

extern "C" void kernel_launch(void* const* d_in, const int* in_sizes, int n_in,
                              void* d_out, int out_size, void* d_ws, size_t ws_size,
                              hipStream_t stream) {
  const float* x = (const float*)d_in[0];
  const float* logits = (const float*)d_in[1];
  const float* Wq1 = (const float*)d_in[2];
  const float* Wk1 = (const float*)d_in[3];
  const float* Wv1 = (const float*)d_in[4];
  const float* Wq2 = (const float*)d_in[5];
  const float* Wk2 = (const float*)d_in[6];
  const float* Wv2 = (const float*)d_in[7];
  const float* Wq3 = (const float*)d_in[8];
  const float* Wk3 = (const float*)d_in[9];
  const float* Wv3 = (const float*)d_in[10];
  const float* ln_w = (const float*)d_in[11];
  const float* ln_b = (const float*)d_in[12];
  const float* conv0_w = (const float*)d_in[13];
  const float* conv0_b = (const float*)d_in[14];
  const float* bn_w = (const float*)d_in[15];
  const float* bn_b = (const float*)d_in[16];
  const float* fc1_w = (const float*)d_in[17];
  const float* fc1_b = (const float*)d_in[18];
  const float* fc2_w = (const float*)d_in[19];
  const float* fc2_b = (const float*)d_in[20];
  float* out = (float*)d_out;

  char* p = (char*)d_ws;
  auto alloc = [&](size_t bytes) {
    char* r = p;
    p += (bytes + 255) & ~(size_t)255;
    return r;
  };
  signed char* kbin = (signed char*)alloc(Bdim * Ndim);
  int* cnt = (int*)alloc(Bdim * Kdim * 4);
  float* pooled = (float*)alloc(Bdim * Cdim * Kdim * 4);
  float* sxx = (float*)alloc(Bdim * Cdim * 4);
  float* feat = (float*)alloc(Bdim * Cdim * Kdim * 4);
  float* mu_i = (float*)alloc(Bdim * Cdim * 4);
  float* rs_i = (float*)alloc(Bdim * Cdim * 4);
  float* ratio = (float*)alloc(Bdim * Cdim * 4);
  float* alpha = (float*)alloc(Bdim * Cdim * 4);
  float* beta = (float*)alloc(Bdim * Cdim * 4);
  unsigned short* Wh = (unsigned short*)alloc(Cdim * Cdim * 2);
  unsigned short* Wlo = (unsigned short*)alloc(Cdim * Cdim * 2);
  unsigned short* Whs = (unsigned short*)alloc(Cdim * Cdim * 2);
  unsigned short* Wls = (unsigned short*)alloc(Cdim * Cdim * 2);
  unsigned short* Wbf = (unsigned short*)alloc(9 * Cdim * Cdim * 2);  // 288KB bf16
  float* f2g = (float*)alloc(Bdim * Cdim * 4);
  float* gmean = (float*)alloc(Bdim * Cdim * 4);
  float* warmdummy = (float*)alloc(576 * 4 * 4);
  unsigned short* gpack = (unsigned short*)alloc((size_t)Bdim * Cdim * Ndim * 2);  // 32 MiB
  bool fast = ((size_t)(p - (char*)d_ws) <= ws_size);

  k_prep<<<640, 256, 0, stream>>>(conv0_w, Wh, Wlo, Whs, Wls,
                                  Wq1, Wk1, Wv1, Wq2, Wk2, Wv2, Wq3, Wk3, Wv3,
                                  Wbf, cnt, gmean);
  k_bin<<<Bdim * Ndim / 256, 256, 0, stream>>>(logits, kbin, cnt);
  k_pool<<<Bdim * Cdim, 256, 0, stream>>>(x, kbin, pooled, sxx);
  // warm bf16 W into every XCD's L2 AFTER k_pool's 67MB stream evicted it
  k_warm<<<576, 256, 0, stream>>>(Wbf, warmdummy);
  k_xform<<<Bdim, 1024, 0, stream>>>(pooled, cnt, sxx, Wbf, ln_w, ln_b,
                                     feat, mu_i, rs_i, ratio);
  if (fast) {
    k_gpack<<<Bdim * 128, 256, 0, stream>>>(x, kbin, feat, mu_i, rs_i, ratio, bn_w, bn_b,
                                            gpack, gmean);
    k_mlp<<<Bdim, 128, 0, stream>>>(gmean, conv0_w, conv0_b, fc1_w, fc1_b, fc2_w, fc2_b,
                                    1.0f / Ndim, f2g);
    k_conv_g<<<256, 1024, 0, stream>>>(gpack, Whs, Wls, conv0_b, f2g, out);
  } else {
    k_alpha<<<1, 128, 0, stream>>>(mu_i, rs_i, ratio, bn_w, bn_b, alpha, beta);
    k_gmean<<<Bdim * Cdim, 256, 0, stream>>>(x, kbin, feat, alpha, beta, gmean);
    k_mlp<<<Bdim, 128, 0, stream>>>(gmean, conv0_w, conv0_b, fc1_w, fc1_b, fc2_w, fc2_b,
                                    1.0f, f2g);
    k_conv_x<<<Bdim * (Ndim / 128), 512, 0, stream>>>(x, kbin, feat, alpha, beta, Wh, Wlo,
                                                      conv0_b, f2g, out);
  }
}